// Round 4
// baseline (353.990 us; speedup 1.0000x reference)
//
#include <hip/hip_runtime.h>

typedef unsigned short u16;
typedef unsigned int   u32;

#define H    128
#define C    16
#define ODIM 128

typedef short bf16x8 __attribute__((ext_vector_type(8)));
typedef float f32x4  __attribute__((ext_vector_type(4)));
typedef float f32x2v __attribute__((ext_vector_type(2)));

#define WSP 272      // Ws row stride (u16)
#define NP  256      // scatter partitions
#define NSH 16       // stat shards
#define SLOT 64      // padded-CSR slots per node
#define OVFCAP 65536 // overflow list capacity

__device__ __forceinline__ float bf2f(u32 v){
  union { u32 i; float f; } t; t.i = v << 16; return t.f;
}
__device__ __forceinline__ u16 f2bf(float f){
  u32 u = __float_as_uint(f);
  u32 r = u + 0x7fffu + ((u >> 16) & 1u);   // RNE
  return (u16)(r >> 16);
}
__device__ __forceinline__ u32 pack2(float a, float b){
  return (u32)f2bf(a) | ((u32)f2bf(b) << 16);
}
__device__ __forceinline__ u32 pack_fp8x4(float a, float b, float c, float d){
  int p = __builtin_amdgcn_cvt_pk_fp8_f32(a, b, 0, false);
  p     = __builtin_amdgcn_cvt_pk_fp8_f32(c, d, p, true);
  return (u32)p;
}

// ---------- k_zero: statsh-zero | bounds | wprep | cnt-zero ----------
__global__ __launch_bounds__(256) void k_zero(const int* __restrict__ batch,
    int* __restrict__ gs, const float* __restrict__ Wl,
    const float* __restrict__ Wr, u16* __restrict__ Wt,
    float* __restrict__ statsh, int* __restrict__ cnt, int* __restrict__ ocnt,
    int N, int B, int z0, int z1, int z2){
  __shared__ __align__(16) char smem[4608];
  int bid = blockIdx.x, tid = threadIdx.x;
  if (bid < z0){
    // ---- zero stat shards ----
    statsh[bid*256 + tid] = 0.f;
  } else if (bid < z1){
    // ---- graph bounds ----
    int n = (bid - z0)*256 + tid;
    if (n < N){
      int b = batch[n];
      if (n == 0){ for (int g = 0; g <= b; g++) gs[g] = 0; }
      else {
        int pb = batch[n-1];
        for (int g = pb+1; g <= b; g++) gs[g] = n;
      }
      if (n == N-1){ for (int g = b+1; g <= B; g++) gs[g] = N; }
    }
  } else if (bid < z2){
    // ---- wprep: Wt[l][h][k] ----
    u16 (*T)[18] = (u16(*)[18])smem;
    int b = bid - z1;
    int strip = b & 7, half = (b >> 3) & 1, l = b >> 4;
    const float* M = (half ? Wr : Wl) + (size_t)l*H*H;
    int k0 = strip * 16;
    #pragma unroll
    for (int j = 0; j < 8; j++){
      int u = tid + j*256;
      int kk = u >> 7, h = u & 127;
      T[h][kk] = f2bf(M[(size_t)(k0 + kk)*H + h]);
    }
    __syncthreads();
    #pragma unroll
    for (int j = 0; j < 8; j++){
      int u = tid + j*256;
      int h = u >> 4, k16 = u & 15;
      Wt[((size_t)(l*H + h))*256 + half*128 + k0 + k16] = T[h][k16];
    }
  } else {
    // ---- zero per-node counters (+ overflow counter) ----
    int n = (bid - z2)*256 + tid;
    if (n < N) cnt[n] = 0;
    if (bid == z2 && tid == 0) *ocnt = 0;
  }
}

// ---------- k_embed_scatter: embed | padded-CSR scatter ----------
__global__ __launch_bounds__(256) void k_embed_scatter(
    const float* __restrict__ emb, const int* __restrict__ deg,
    u16* __restrict__ xb, u32* __restrict__ xq, const int* __restrict__ ei,
    int* __restrict__ cnt, int* __restrict__ colp, int2* __restrict__ ovf,
    int* __restrict__ ocnt, int N, int E, int chunk, int e0){
  int bid = blockIdx.x, tid = threadIdx.x;
  if (bid < e0){
    // ---- embed ----
    int i = bid*256 + tid;
    if (i < N*32){
      int n = i >> 5, q = i & 31;
      int d = deg[n];
      float4 v = ((const float4*)(emb + (size_t)d*H))[q];
      uint2 o; o.x = pack2(v.x, v.y); o.y = pack2(v.z, v.w);
      ((uint2*)(xb + (size_t)n*H))[q] = o;
      xq[i] = pack_fp8x4(v.x, v.y, v.z, v.w);
    }
  } else {
    // ---- edge scatter into padded CSR ----
    int blk = bid - e0;
    int start = blk*chunk, end = min(E, start + chunk);
    for (int e = start + tid; e < end; e += 256){
      int s = ei[e], d = ei[E + e];
      int r = atomicAdd(&cnt[d], 1);
      if (r < SLOT) colp[(size_t)d*SLOT + r] = s;
      else {
        int o = atomicAdd(ocnt, 1);
        if (o < OVFCAP) ovf[o] = make_int2(s, d);
      }
    }
  }
}

// ---------------- per-layer ----------------
// wave per node; fp8 row = 128 B = 8 lanes x uint4, 8 edges/VMEM-instr,
// packed f32 accumulate (v_pk_add_f32).
__device__ __forceinline__ void dec16v(f32x2v* a, uint4 v){
  a[0] += __builtin_amdgcn_cvt_pk_f32_fp8((int)v.x, false);
  a[1] += __builtin_amdgcn_cvt_pk_f32_fp8((int)v.x, true );
  a[2] += __builtin_amdgcn_cvt_pk_f32_fp8((int)v.y, false);
  a[3] += __builtin_amdgcn_cvt_pk_f32_fp8((int)v.y, true );
  a[4] += __builtin_amdgcn_cvt_pk_f32_fp8((int)v.z, false);
  a[5] += __builtin_amdgcn_cvt_pk_f32_fp8((int)v.z, true );
  a[6] += __builtin_amdgcn_cvt_pk_f32_fp8((int)v.w, false);
  a[7] += __builtin_amdgcn_cvt_pk_f32_fp8((int)v.w, true );
}

__global__ __launch_bounds__(256) void k_agg(const u32* __restrict__ xq,
    const int* __restrict__ cnt, const int* __restrict__ colp,
    const int2* __restrict__ ovf, const int* __restrict__ ocntp,
    u16* __restrict__ meanb, int N){
  int wid  = (blockIdx.x*256 + threadIdx.x) >> 6;
  int lane = threadIdx.x & 63;
  if (wid >= N) return;
  int cn = cnt[wid];
  int m  = min(cn, SLOT);
  int r0 = wid*SLOT;
  int grp = lane >> 3, fl = lane & 7;   // 8 groups x 8 lanes
  const u32* xf = xq + fl*4;            // 16 fp8 features per lane
  f32x2v a[8];
  #pragma unroll
  for (int j = 0; j < 8; j++) a[j] = (f32x2v){0.f, 0.f};
  int e = grp;
  for (; e + 8 < m; e += 16){
    uint4 v = *(const uint4*)(xf + (size_t)colp[r0 + e]*32);
    uint4 u = *(const uint4*)(xf + (size_t)colp[r0 + e + 8]*32);
    dec16v(a, v);
    dec16v(a, u);
  }
  if (e < m){
    uint4 v = *(const uint4*)(xf + (size_t)colp[r0 + e]*32);
    dec16v(a, v);
  }
  if (cn > SLOT){
    // rare overflow replay (counted once: only grp 0 accumulates)
    int oc = min(*ocntp, OVFCAP);
    for (int i = 0; i < oc; i++){
      int2 p = ovf[i];
      if (p.y == wid && grp == 0){
        uint4 v = *(const uint4*)(xf + (size_t)p.x*32);
        dec16v(a, v);
      }
    }
  }
  #pragma unroll
  for (int j = 0; j < 8; j++){
    a[j].x += __shfl_xor(a[j].x, 8, 64);  a[j].y += __shfl_xor(a[j].y, 8, 64);
    a[j].x += __shfl_xor(a[j].x, 16, 64); a[j].y += __shfl_xor(a[j].y, 16, 64);
    a[j].x += __shfl_xor(a[j].x, 32, 64); a[j].y += __shfl_xor(a[j].y, 32, 64);
  }
  if (grp == 0){
    float invc = 1.0f / (float)max(cn, 1);
    uint4 o0, o1;
    o0.x = pack2(a[0].x*invc, a[0].y*invc);
    o0.y = pack2(a[1].x*invc, a[1].y*invc);
    o0.z = pack2(a[2].x*invc, a[2].y*invc);
    o0.w = pack2(a[3].x*invc, a[3].y*invc);
    o1.x = pack2(a[4].x*invc, a[4].y*invc);
    o1.y = pack2(a[5].x*invc, a[5].y*invc);
    o1.z = pack2(a[6].x*invc, a[6].y*invc);
    o1.w = pack2(a[7].x*invc, a[7].y*invc);
    u16* mp = meanb + (size_t)wid*H + fl*16;
    *(uint4*)mp       = o0;
    *(uint4*)(mp + 8) = o1;
  }
}

// x2b[n][h] (bf16) = bl[h] + [meanb|xb] @ Wt^T via mfma_f32_16x16x32_bf16.
// Wt staged whole in LDS; A-fragments direct from global. BN-stat block sums
// -> 16 global atomic shards (49-deep chains; NO fences).
__global__ __launch_bounds__(256) void k_linear(const u16* __restrict__ meanb,
    const u16* __restrict__ xb, const u16* __restrict__ Wt,
    const float* __restrict__ bl, u16* __restrict__ x2b,
    float* __restrict__ statsh_l, int N){
  __shared__ u16 Ws[128][WSP];         // 69.6 KB -> 2 blocks/CU
  __shared__ float Sh[128], Qh[128];
  int tid = threadIdx.x;
  if (tid < 128){ Sh[tid] = 0.f; Qh[tid] = 0.f; }
  int lane = tid & 63, w = tid >> 6;
  int mlane = lane & 15, quad = lane >> 4;
  int node = blockIdx.x*64 + w*16 + mlane;
  const u16* arow_m = meanb + (size_t)node*H + quad*8;
  const u16* arow_x = xb   + (size_t)node*H + quad*8;
  bf16x8 af[8];
  #pragma unroll
  for (int kk = 0; kk < 4; kk++){
    af[kk]     = *(const bf16x8*)(arow_m + kk*32);
    af[kk + 4] = *(const bf16x8*)(arow_x + kk*32);
  }
  #pragma unroll
  for (int j = 0; j < 16; j++){
    int u = tid + j*256;
    int row = u >> 5, seg = u & 31;
    uint4 v = ((const uint4*)(Wt + (size_t)row*256))[seg];
    *(uint4*)&Ws[row][seg*8] = v;
  }
  __syncthreads();
  f32x4 acc[8];
  #pragma unroll
  for (int t = 0; t < 8; t++) acc[t] = (f32x4){0.f, 0.f, 0.f, 0.f};
  #pragma unroll
  for (int kk = 0; kk < 8; kk++){
    #pragma unroll
    for (int t = 0; t < 8; t++){
      bf16x8 b = *(const bf16x8*)&Ws[t*16 + mlane][kk*32 + quad*8];
      acc[t] = __builtin_amdgcn_mfma_f32_16x16x32_bf16(af[kk], b, acc[t], 0, 0, 0);
    }
  }
  #pragma unroll
  for (int t = 0; t < 8; t++){
    int h = t*16 + mlane;
    float bv = bl[h];
    float s = 0.f, q = 0.f;
    #pragma unroll
    for (int r = 0; r < 4; r++){
      int nd = blockIdx.x*64 + w*16 + quad*4 + r;
      if (nd < N){
        float v = acc[t][r] + bv;
        x2b[(size_t)nd*H + h] = f2bf(v);
        s += v; q = fmaf(v, v, q);
      }
    }
    s += __shfl_xor(s, 16, 64); s += __shfl_xor(s, 32, 64);
    q += __shfl_xor(q, 16, 64); q += __shfl_xor(q, 32, 64);
    if (quad == 0){
      atomicAdd(&Sh[h], s);
      atomicAdd(&Qh[h], q);
    }
  }
  __syncthreads();
  {
    float v = (tid < 128) ? Sh[tid] : Qh[tid - 128];
    atomicAdd(&statsh_l[(blockIdx.x & (NSH-1))*256 + tid], v);
  }
}

// BN+ReLU (reads bf16 x2b); sums 16 stat shards into LDS at start;
// writes xb (+ xq, except on the last layer: nothing ever reads it after);
// do_scores fuses attention scores.
__global__ __launch_bounds__(256) void k_bnrelu(const u16* __restrict__ x2b,
    const float* __restrict__ statsh_l, const float* __restrict__ gamma,
    const float* __restrict__ beta, u16* __restrict__ xb, u32* __restrict__ xq,
    int N, float invN,
    const float* __restrict__ attn_W, const float* __restrict__ attn_b,
    float* __restrict__ escore, int do_scores){
  __shared__ float st[256];
  __shared__ float xs[8][132];
  __shared__ float aw[H*C];
  __shared__ float ab[C];
  int tid = threadIdx.x;
  {
    float sacc = 0.f;
    #pragma unroll
    for (int s2 = 0; s2 < NSH; s2++) sacc += statsh_l[s2*256 + tid];
    st[tid] = sacc;
  }
  __syncthreads();
  int i = blockIdx.x*256 + tid;
  bool active = (i < N*32);
  int h = (tid & 31) * 4;
  float r[4] = {0.f, 0.f, 0.f, 0.f};
  if (active){
    uint2 o2 = ((const uint2*)x2b)[i];
    float vv[4] = {bf2f(o2.x & 0xffff), bf2f(o2.x >> 16),
                   bf2f(o2.y & 0xffff), bf2f(o2.y >> 16)};
    #pragma unroll
    for (int j = 0; j < 4; j++){
      float mu  = st[h+j] * invN;
      float var = fmaf(-mu, mu, st[H + h + j] * invN);
      float sc  = rsqrtf(var + 1e-5f) * gamma[h+j];
      float bi  = beta[h+j];
      r[j] = fmaxf(fmaf(vv[j] - mu, sc, bi), 0.0f);
    }
    uint2 o; o.x = pack2(r[0], r[1]); o.y = pack2(r[2], r[3]);
    ((uint2*)xb)[i] = o;
    if (!do_scores) xq[i] = pack_fp8x4(r[0], r[1], r[2], r[3]);
  }
  if (do_scores){
    #pragma unroll
    for (int j = 0; j < 8; j++) aw[tid + j*256] = attn_W[tid + j*256];
    if (tid < C) ab[tid] = attn_b[tid];
    int ln = tid >> 5;
    if (active){
      xs[ln][h+0]=r[0]; xs[ln][h+1]=r[1]; xs[ln][h+2]=r[2]; xs[ln][h+3]=r[3];
    }
    __syncthreads();
    if (tid < 128){
      int n2 = tid >> 4, c = tid & 15;
      int node = blockIdx.x*8 + n2;
      if (node < N){
        float acc = ab[c];
        #pragma unroll 4
        for (int k = 0; k < H; k++)
          acc = fmaf(xs[n2][k], aw[k*C + c], acc);
        escore[(size_t)node*C + c] = __expf(acc);
      }
    }
  }
}

// partial[g][b][c][h] = strided-node partial of escore[n][c]*x[n][h]
__global__ __launch_bounds__(256) void k_clust(const u16* __restrict__ xb,
    const float* __restrict__ escore, const int* __restrict__ gs,
    float* __restrict__ partial){
  int g = blockIdx.x >> 4, b = blockIdx.x & 15;
  int h = threadIdx.x & 127, cg = threadIdx.x >> 7;
  int a = gs[g], e2 = gs[g+1];
  float acc[8] = {0,0,0,0,0,0,0,0};
  for (int n = a + b; n < e2; n += 16){
    float xv = bf2f(xb[(size_t)n*H + h]);
    const float4* ep = (const float4*)(escore + (size_t)n*C) + cg*2;
    float4 e0 = ep[0], e1 = ep[1];
    acc[0] = fmaf(e0.x, xv, acc[0]);
    acc[1] = fmaf(e0.y, xv, acc[1]);
    acc[2] = fmaf(e0.z, xv, acc[2]);
    acc[3] = fmaf(e0.w, xv, acc[3]);
    acc[4] = fmaf(e1.x, xv, acc[4]);
    acc[5] = fmaf(e1.y, xv, acc[5]);
    acc[6] = fmaf(e1.z, xv, acc[6]);
    acc[7] = fmaf(e1.w, xv, acc[7]);
  }
  int c0 = cg*8;
  float* dst = partial + (((size_t)(g*16 + b))*C)*H + h;
  #pragma unroll
  for (int r = 0; r < 8; r++)
    dst[(size_t)(c0 + r)*H] = acc[r];
}

// k_out with fused denom (sum of escore over the graph's nodes per cluster)
__global__ __launch_bounds__(256) void k_out(const float* __restrict__ partial,
    const float* __restrict__ escore, const int* __restrict__ gs,
    const float* __restrict__ out_W, const float* __restrict__ out_b,
    float* __restrict__ out){
  __shared__ float cs[2][128];
  __shared__ float dsum[4];
  int tid = threadIdx.x;
  int r = tid >> 7, h = tid & 127;
  int row = blockIdx.x*2 + r;          // (g,c) flat
  int g = row >> 4, c = row & 15;
  int a = gs[g], b2 = gs[g+1];
  // denom
  float s = 0.f;
  for (int n = a + h; n < b2; n += 128) s += escore[(size_t)n*C + c];
  s += __shfl_xor(s, 1, 64);  s += __shfl_xor(s, 2, 64);
  s += __shfl_xor(s, 4, 64);  s += __shfl_xor(s, 8, 64);
  s += __shfl_xor(s, 16, 64); s += __shfl_xor(s, 32, 64);
  if ((tid & 63) == 0) dsum[tid >> 6] = s;
  // cluster sum reduce
  float p = 0.f;
  for (int b = 0; b < 16; b++)
    p += partial[(((size_t)(g*16 + b))*C + c)*H + h];
  cs[r][h] = p;
  __syncthreads();
  float gden = dsum[r*2] + dsum[r*2 + 1];
  float inv = gden > 0.f ? 1.0f / gden : 0.f;
  float acc = 0.f;
  for (int hh = 0; hh < H; hh++)
    acc = fmaf(cs[r][hh], out_W[hh*ODIM + h], acc);
  out[(size_t)row*ODIM + h] = fmaf(acc, inv, out_b[h]);
}

// ---------------- host ----------------
extern "C" void kernel_launch(void* const* d_in, const int* in_sizes, int n_in,
                              void* d_out, int out_size, void* d_ws, size_t ws_size,
                              hipStream_t stream){
  const float* emb    = (const float*)d_in[0];
  const float* Wl     = (const float*)d_in[1];
  const float* bl     = (const float*)d_in[2];
  const float* Wr     = (const float*)d_in[3];
  const float* gamma  = (const float*)d_in[4];
  const float* beta   = (const float*)d_in[5];
  const float* attn_W = (const float*)d_in[6];
  const float* attn_b = (const float*)d_in[7];
  const float* out_W  = (const float*)d_in[8];
  const float* out_b  = (const float*)d_in[9];
  const int* deg    = (const int*)d_in[10];
  const int* ei     = (const int*)d_in[11];
  const int* batch  = (const int*)d_in[12];
  float* out = (float*)d_out;

  const int N = in_sizes[10];
  const int E = in_sizes[11] / 2;
  const int L = in_sizes[1] / (H*H);
  const int B = out_size / (C*ODIM);
  const int chunk = (E + NP - 1) / NP;  // edges per scatter block
  const int nblkL = (N + 63) / 64;      // k_linear grid

  size_t off = 0;
  auto alloc = [&](size_t bytes) -> void* {
    void* p = (char*)d_ws + off;
    off += (bytes + 255) & ~(size_t)255;
    return p;
  };
  u16*   xb     = (u16*)  alloc((size_t)N*H*2);
  u32*   xq     = (u32*)  alloc((size_t)N*H);    // fp8 shadow of xb
  u16*   meanb  = (u16*)  alloc((size_t)N*H*2);
  u16*   x2b    = (u16*)  alloc((size_t)N*H*2);
  float* partial= (float*)alloc((size_t)B*16*C*H*4);  // dedicated (8.4 MB)
  u16*   Wt     = (u16*)  alloc((size_t)L*H*256*2);
  float* escore = (float*)alloc((size_t)N*C*4);
  int*   colp   = (int*)  alloc((size_t)N*SLOT*4);    // padded CSR (12.8 MB)
  int*   cnt    = (int*)  alloc((size_t)N*4);
  int2*  ovf    = (int2*) alloc((size_t)OVFCAP*8);
  int*   ocnt   = (int*)  alloc(256);
  int*   gs     = (int*)  alloc((size_t)(B+1)*4);
  float* statsh = (float*)alloc((size_t)L*NSH*256*4); // stat shards

  // k_zero virtual grid: statsh | bounds | wprep | cnt-zero
  int z0 = L*NSH;
  int z1 = z0 + (N + 255)/256;
  int z2 = z1 + L*16;
  int zT = z2 + (N + 255)/256;
  hipLaunchKernelGGL(k_zero, dim3(zT), dim3(256), 0, stream,
                     batch, gs, Wl, Wr, Wt, statsh, cnt, ocnt, N, B, z0, z1, z2);

  // k_embed_scatter virtual grid: embed | scatter
  int e0 = (N*32 + 255)/256;
  int eT = e0 + NP;
  hipLaunchKernelGGL(k_embed_scatter, dim3(eT), dim3(256), 0, stream,
                     emb, deg, xb, xq, ei, cnt, colp, ovf, ocnt, N, E, chunk, e0);

  float invN = 1.0f / (float)N;
  for (int l = 0; l < L; l++){
    float* sh_l = statsh + (size_t)l*NSH*256;
    hipLaunchKernelGGL(k_agg,    dim3((N+3)/4),  dim3(256), 0, stream,
                       xq, cnt, colp, ovf, ocnt, meanb, N);
    hipLaunchKernelGGL(k_linear, dim3(nblkL),    dim3(256), 0, stream,
                       meanb, xb, Wt + (size_t)l*H*256, bl + (size_t)l*H, x2b,
                       sh_l, N);
    hipLaunchKernelGGL(k_bnrelu, dim3((N*32+255)/256), dim3(256), 0, stream,
                       x2b, sh_l, gamma + (size_t)l*H, beta + (size_t)l*H,
                       xb, xq, N, invN, attn_W, attn_b, escore, (l == L-1) ? 1 : 0);
  }
  hipLaunchKernelGGL(k_clust, dim3(B*16),  dim3(256), 0, stream, xb, escore, gs, partial);
  hipLaunchKernelGGL(k_out,   dim3(B*C/2), dim3(256), 0, stream,
                     partial, escore, gs, out_W, out_b, out);
}

// Round 5
// 341.029 us; speedup vs baseline: 1.0380x; 1.0380x over previous
//
#include <hip/hip_runtime.h>

typedef unsigned short u16;
typedef unsigned int   u32;

#define H    128
#define C    16
#define ODIM 128

typedef short bf16x8 __attribute__((ext_vector_type(8)));
typedef float f32x4  __attribute__((ext_vector_type(4)));
typedef float f32x2v __attribute__((ext_vector_type(2)));

#define WSP 272   // Ws row stride (u16)
#define NP  256   // CSR partitions
#define NSH 16    // stat shards
#define GSB 2048  // grid-stride block cap (8 blocks/CU)

__device__ __forceinline__ float bf2f(u32 v){
  union { u32 i; float f; } t; t.i = v << 16; return t.f;
}
__device__ __forceinline__ u16 f2bf(float f){
  u32 u = __float_as_uint(f);
  u32 r = u + 0x7fffu + ((u >> 16) & 1u);   // RNE
  return (u16)(r >> 16);
}
__device__ __forceinline__ u32 pack2(float a, float b){
  return (u32)f2bf(a) | ((u32)f2bf(b) << 16);
}
__device__ __forceinline__ u32 pack_fp8x4(float a, float b, float c, float d){
  int p = __builtin_amdgcn_cvt_pk_fp8_f32(a, b, 0, false);
  p     = __builtin_amdgcn_cvt_pk_fp8_f32(c, d, p, true);
  return (u32)p;
}

// ---------- fused setup (grid-stride): shard-zero | embed | bounds | wprep | hist ----------
__global__ __launch_bounds__(256) void k_setup(const float* __restrict__ emb,
    const int* __restrict__ deg, u16* __restrict__ xb, u32* __restrict__ xq,
    const int* __restrict__ batch, int* __restrict__ gs,
    const float* __restrict__ Wl, const float* __restrict__ Wr,
    u16* __restrict__ Wt, const int* __restrict__ ei,
    int* __restrict__ blkhist, float* __restrict__ statsh,
    int N, int B, int NB, int E, int chunk,
    int gz, int g0, int g1, int g2, int gT){
  __shared__ __align__(16) char smem[4608];
  int tid = threadIdx.x;
  for (int bid = blockIdx.x; bid < gT; bid += gridDim.x){
    if (bid < gz){
      // ---- zero stat shards ----
      statsh[bid*256 + tid] = 0.f;
    } else if (bid < g0){
      // ---- embed ----
      int i = (bid - gz)*256 + tid;
      if (i < N*32){
        int n = i >> 5, q = i & 31;
        int d = deg[n];
        float4 v = ((const float4*)(emb + (size_t)d*H))[q];
        uint2 o; o.x = pack2(v.x, v.y); o.y = pack2(v.z, v.w);
        ((uint2*)(xb + (size_t)n*H))[q] = o;
        xq[i] = pack_fp8x4(v.x, v.y, v.z, v.w);
      }
    } else if (bid < g1){
      // ---- bounds ----
      int n = (bid - g0)*256 + tid;
      if (n < N){
        int b = batch[n];
        if (n == 0){ for (int g = 0; g <= b; g++) gs[g] = 0; }
        else {
          int pb = batch[n-1];
          for (int g = pb+1; g <= b; g++) gs[g] = n;
        }
        if (n == N-1){ for (int g = b+1; g <= B; g++) gs[g] = N; }
      }
    } else if (bid < g2){
      // ---- wprep: Wt[l][h][k] ----
      u16 (*T)[18] = (u16(*)[18])smem;
      int b = bid - g1;
      int strip = b & 7, half = (b >> 3) & 1, l = b >> 4;
      const float* M = (half ? Wr : Wl) + (size_t)l*H*H;
      int k0 = strip * 16;
      #pragma unroll
      for (int j = 0; j < 8; j++){
        int u = tid + j*256;
        int kk = u >> 7, h = u & 127;
        T[h][kk] = f2bf(M[(size_t)(k0 + kk)*H + h]);
      }
      __syncthreads();
      #pragma unroll
      for (int j = 0; j < 8; j++){
        int u = tid + j*256;
        int h = u >> 4, k16 = u & 15;
        Wt[((size_t)(l*H + h))*256 + half*128 + k0 + k16] = T[h][k16];
      }
    } else {
      // ---- hist ----
      int* hist = (int*)smem;
      int blk = bid - g2;
      for (int b = tid; b < NB; b += 256) hist[b] = 0;
      __syncthreads();
      int start = blk*chunk, end = min(E, start + chunk);
      for (int e = start + tid; e < end; e += 256)
        atomicAdd(&hist[ei[E + e] >> 7], 1);
      __syncthreads();
      for (int b = tid; b < NB; b += 256) blkhist[b*NP + blk] = hist[b];
    }
    __syncthreads();   // protect smem reuse across grid-stride iterations
  }
}

// generic scan over n ints (1024 per block); writes per-block totals to bsum
__global__ __launch_bounds__(256) void k_scanA(const int* __restrict__ in,
    int* __restrict__ out, int* __restrict__ bsum, int n){
  __shared__ int wsum[4];
  int tid = threadIdx.x;
  int base = blockIdx.x*1024 + tid*4;
  int v0 = (base+0 < n) ? in[base+0] : 0;
  int v1 = (base+1 < n) ? in[base+1] : 0;
  int v2 = (base+2 < n) ? in[base+2] : 0;
  int v3 = (base+3 < n) ? in[base+3] : 0;
  int tsum = v0+v1+v2+v3;
  int lane = tid & 63, w = tid >> 6;
  int incl = tsum;
  for (int d = 1; d < 64; d <<= 1){
    int t = __shfl_up(incl, d, 64);
    if (lane >= d) incl += t;
  }
  if (lane == 63) wsum[w] = incl;
  __syncthreads();
  int woff = 0;
  for (int i = 0; i < w; i++) woff += wsum[i];
  int excl = woff + incl - tsum;
  if (base+0 < n) out[base+0] = excl;
  if (base+1 < n) out[base+1] = excl + v0;
  if (base+2 < n) out[base+2] = excl + v0 + v1;
  if (base+3 < n) out[base+3] = excl + v0 + v1 + v2;
  if (tid == 255) bsum[blockIdx.x] = woff + incl;
}

// in-block exclusive scan of bsum[0..nb) -> bo[0..255] (nb <= 256)
__device__ __forceinline__ void scan_bsum(const int* __restrict__ bsum,
    int* bo, int nb, int tid){
  __shared__ int ws2[4];
  int v = (tid < nb) ? bsum[tid] : 0;
  int lane = tid & 63, w = tid >> 6;
  int incl = v;
  for (int d = 1; d < 64; d <<= 1){
    int t = __shfl_up(incl, d, 64);
    if (lane >= d) incl += t;
  }
  if (lane == 63) ws2[w] = incl;
  __syncthreads();
  int woff = 0;
  for (int i = 0; i < w; i++) woff += ws2[i];
  bo[tid] = woff + incl - v;
  __syncthreads();
}

// place edges bucket-sorted as (src,dst) pairs; boff computed locally
__global__ __launch_bounds__(256) void k_place(const int* __restrict__ ei,
    const int* __restrict__ bases, const int* __restrict__ bsum,
    int2* __restrict__ pairs, int NB, int E, int chunk, int nbs){
  __shared__ int cursor[400];
  __shared__ int bo[256];
  int blk = blockIdx.x, tid = threadIdx.x;
  scan_bsum(bsum, bo, nbs, tid);
  for (int b = tid; b < NB; b += 256){
    int i = b*NP + blk;
    cursor[b] = bases[i] + bo[i >> 10];
  }
  __syncthreads();
  int start = blk*chunk, end = min(E, start + chunk);
  for (int e = start + tid; e < end; e += 256){
    int s = ei[e], d = ei[E + e];
    int pos = atomicAdd(&cursor[d >> 7], 1);
    pairs[pos] = make_int2(s, d);
  }
}

// per bucket: per-node counts -> rowptr (direct), then node-sort col
__global__ __launch_bounds__(256) void k_cnt_place(const int2* __restrict__ pairs,
    const int* __restrict__ bases, const int* __restrict__ bsum,
    int* __restrict__ rowptr, int* __restrict__ col,
    int NB, int N, int E, int nbs){
  int b = blockIdx.x, tid = threadIdx.x;
  __shared__ int bo[256];
  scan_bsum(bsum, bo, nbs, tid);
  int i0 = b*NP;
  int bstart = bases[i0] + bo[i0 >> 10];
  int bend = E;
  if (b+1 < NB){ int i1 = (b+1)*NP; bend = bases[i1] + bo[i1 >> 10]; }
  __shared__ int cnt[128], sc[128], rank[128];
  if (tid < 128) cnt[tid] = 0;
  __syncthreads();
  for (int e = bstart + tid; e < bend; e += 256)
    atomicAdd(&cnt[pairs[e].y & 127], 1);
  __syncthreads();
  if (tid < 128) sc[tid] = cnt[tid];
  for (int d = 1; d < 128; d <<= 1){
    int v = 0;
    __syncthreads();
    if (tid < 128 && tid >= d) v = sc[tid - d];
    __syncthreads();
    if (tid < 128) sc[tid] += v;
  }
  __syncthreads();
  if (tid < 128){
    int excl = sc[tid] - cnt[tid];
    rank[tid] = bstart + excl;
    int node = b*128 + tid;
    if (node < N) rowptr[node] = bstart + excl;
  }
  if (b == NB-1 && tid == 0) rowptr[N] = E;
  __syncthreads();
  for (int e = bstart + tid; e < bend; e += 256){
    int2 p = pairs[e];
    int pos = atomicAdd(&rank[p.y & 127], 1);
    col[pos] = p.x;
  }
}

// ---------------- per-layer ----------------
// wave per node (grid-stride over nodes); fp8 row = 128 B = 8 lanes x uint4,
// 8 edges/VMEM-instr, packed f32 accumulate (v_pk_add_f32).
__device__ __forceinline__ void dec16v(f32x2v* a, uint4 v){
  a[0] += __builtin_amdgcn_cvt_pk_f32_fp8((int)v.x, false);
  a[1] += __builtin_amdgcn_cvt_pk_f32_fp8((int)v.x, true );
  a[2] += __builtin_amdgcn_cvt_pk_f32_fp8((int)v.y, false);
  a[3] += __builtin_amdgcn_cvt_pk_f32_fp8((int)v.y, true );
  a[4] += __builtin_amdgcn_cvt_pk_f32_fp8((int)v.z, false);
  a[5] += __builtin_amdgcn_cvt_pk_f32_fp8((int)v.z, true );
  a[6] += __builtin_amdgcn_cvt_pk_f32_fp8((int)v.w, false);
  a[7] += __builtin_amdgcn_cvt_pk_f32_fp8((int)v.w, true );
}

__global__ __launch_bounds__(256) void k_agg(const u32* __restrict__ xq,
    const int* __restrict__ rowptr, const int* __restrict__ col,
    u16* __restrict__ meanb, int N){
  int wid0 = (blockIdx.x*256 + threadIdx.x) >> 6;
  int nwav = gridDim.x << 2;           // waves in grid
  int lane = threadIdx.x & 63;
  int grp = lane >> 3, fl = lane & 7;   // 8 groups x 8 lanes
  const u32* xf = xq + fl*4;            // 16 fp8 features per lane
  for (int wid = wid0; wid < N; wid += nwav){
    int r0 = rowptr[wid], r1 = rowptr[wid+1];
    f32x2v a[8];
    #pragma unroll
    for (int j = 0; j < 8; j++) a[j] = (f32x2v){0.f, 0.f};
    int e = r0 + grp;
    for (; e + 8 < r1; e += 16){
      uint4 v = *(const uint4*)(xf + (size_t)col[e]*32);
      uint4 u = *(const uint4*)(xf + (size_t)col[e+8]*32);
      dec16v(a, v);
      dec16v(a, u);
    }
    if (e < r1){
      uint4 v = *(const uint4*)(xf + (size_t)col[e]*32);
      dec16v(a, v);
    }
    #pragma unroll
    for (int j = 0; j < 8; j++){
      a[j].x += __shfl_xor(a[j].x, 8, 64);  a[j].y += __shfl_xor(a[j].y, 8, 64);
      a[j].x += __shfl_xor(a[j].x, 16, 64); a[j].y += __shfl_xor(a[j].y, 16, 64);
      a[j].x += __shfl_xor(a[j].x, 32, 64); a[j].y += __shfl_xor(a[j].y, 32, 64);
    }
    if (grp == 0){
      float invc = 1.0f / (float)max(r1 - r0, 1);
      uint4 o0, o1;
      o0.x = pack2(a[0].x*invc, a[0].y*invc);
      o0.y = pack2(a[1].x*invc, a[1].y*invc);
      o0.z = pack2(a[2].x*invc, a[2].y*invc);
      o0.w = pack2(a[3].x*invc, a[3].y*invc);
      o1.x = pack2(a[4].x*invc, a[4].y*invc);
      o1.y = pack2(a[5].x*invc, a[5].y*invc);
      o1.z = pack2(a[6].x*invc, a[6].y*invc);
      o1.w = pack2(a[7].x*invc, a[7].y*invc);
      u16* mp = meanb + (size_t)wid*H + fl*16;
      *(uint4*)mp       = o0;
      *(uint4*)(mp + 8) = o1;
    }
  }
}

// x2b[n][h] (bf16) = bl[h] + [meanb|xb] @ Wt^T via mfma_f32_16x16x32_bf16.
// Wt staged whole in LDS; A-fragments direct from global. BN-stat block sums
// -> 16 global atomic shards (49-deep chains; NO fences).
__global__ __launch_bounds__(256) void k_linear(const u16* __restrict__ meanb,
    const u16* __restrict__ xb, const u16* __restrict__ Wt,
    const float* __restrict__ bl, u16* __restrict__ x2b,
    float* __restrict__ statsh_l, int N){
  __shared__ u16 Ws[128][WSP];         // 69.6 KB -> 2 blocks/CU
  __shared__ float Sh[128], Qh[128];
  int tid = threadIdx.x;
  if (tid < 128){ Sh[tid] = 0.f; Qh[tid] = 0.f; }
  int lane = tid & 63, w = tid >> 6;
  int mlane = lane & 15, quad = lane >> 4;
  int node = blockIdx.x*64 + w*16 + mlane;
  const u16* arow_m = meanb + (size_t)node*H + quad*8;
  const u16* arow_x = xb   + (size_t)node*H + quad*8;
  bf16x8 af[8];
  #pragma unroll
  for (int kk = 0; kk < 4; kk++){
    af[kk]     = *(const bf16x8*)(arow_m + kk*32);
    af[kk + 4] = *(const bf16x8*)(arow_x + kk*32);
  }
  #pragma unroll
  for (int j = 0; j < 16; j++){
    int u = tid + j*256;
    int row = u >> 5, seg = u & 31;
    uint4 v = ((const uint4*)(Wt + (size_t)row*256))[seg];
    *(uint4*)&Ws[row][seg*8] = v;
  }
  __syncthreads();
  f32x4 acc[8];
  #pragma unroll
  for (int t = 0; t < 8; t++) acc[t] = (f32x4){0.f, 0.f, 0.f, 0.f};
  #pragma unroll
  for (int kk = 0; kk < 8; kk++){
    #pragma unroll
    for (int t = 0; t < 8; t++){
      bf16x8 b = *(const bf16x8*)&Ws[t*16 + mlane][kk*32 + quad*8];
      acc[t] = __builtin_amdgcn_mfma_f32_16x16x32_bf16(af[kk], b, acc[t], 0, 0, 0);
    }
  }
  #pragma unroll
  for (int t = 0; t < 8; t++){
    int h = t*16 + mlane;
    float bv = bl[h];
    float s = 0.f, q = 0.f;
    #pragma unroll
    for (int r = 0; r < 4; r++){
      int nd = blockIdx.x*64 + w*16 + quad*4 + r;
      if (nd < N){
        float v = acc[t][r] + bv;
        x2b[(size_t)nd*H + h] = f2bf(v);
        s += v; q = fmaf(v, v, q);
      }
    }
    s += __shfl_xor(s, 16, 64); s += __shfl_xor(s, 32, 64);
    q += __shfl_xor(q, 16, 64); q += __shfl_xor(q, 32, 64);
    if (quad == 0){
      atomicAdd(&Sh[h], s);
      atomicAdd(&Qh[h], q);
    }
  }
  __syncthreads();
  {
    float v = (tid < 128) ? Sh[tid] : Qh[tid - 128];
    atomicAdd(&statsh_l[(blockIdx.x & (NSH-1))*256 + tid], v);
  }
}

// BN+ReLU (grid-stride; reads bf16 x2b); statsh shard-sum hoisted; writes xb
// (+ xq, except last layer); do_scores fuses attention scores.
__global__ __launch_bounds__(256) void k_bnrelu(const u16* __restrict__ x2b,
    const float* __restrict__ statsh_l, const float* __restrict__ gamma,
    const float* __restrict__ beta, u16* __restrict__ xb, u32* __restrict__ xq,
    int N, float invN,
    const float* __restrict__ attn_W, const float* __restrict__ attn_b,
    float* __restrict__ escore, int do_scores){
  __shared__ float st[256];
  __shared__ float xs[8][132];
  __shared__ float aw[H*C];
  __shared__ float ab[C];
  int tid = threadIdx.x;
  {
    float sacc = 0.f;
    #pragma unroll
    for (int s2 = 0; s2 < NSH; s2++) sacc += statsh_l[s2*256 + tid];
    st[tid] = sacc;
  }
  if (do_scores){
    #pragma unroll
    for (int j = 0; j < 8; j++) aw[tid + j*256] = attn_W[tid + j*256];
    if (tid < C) ab[tid] = attn_b[tid];
  }
  __syncthreads();
  int h = (tid & 31) * 4;
  float mu[4], sc[4], bi[4];
  #pragma unroll
  for (int j = 0; j < 4; j++){
    mu[j] = st[h+j] * invN;
    float var = fmaf(-mu[j], mu[j], st[H + h + j] * invN);
    sc[j] = rsqrtf(var + 1e-5f) * gamma[h+j];
    bi[j] = beta[h+j];
  }
  int nvb = (N*32 + 255) >> 8;
  for (int vb = blockIdx.x; vb < nvb; vb += gridDim.x){
    int i = vb*256 + tid;
    bool active = (i < N*32);
    float r[4] = {0.f, 0.f, 0.f, 0.f};
    if (active){
      uint2 o2 = ((const uint2*)x2b)[i];
      float vv[4] = {bf2f(o2.x & 0xffff), bf2f(o2.x >> 16),
                     bf2f(o2.y & 0xffff), bf2f(o2.y >> 16)};
      #pragma unroll
      for (int j = 0; j < 4; j++)
        r[j] = fmaxf(fmaf(vv[j] - mu[j], sc[j], bi[j]), 0.0f);
      uint2 o; o.x = pack2(r[0], r[1]); o.y = pack2(r[2], r[3]);
      ((uint2*)xb)[i] = o;
      if (!do_scores) xq[i] = pack_fp8x4(r[0], r[1], r[2], r[3]);
    }
    if (do_scores){
      int ln = tid >> 5;
      if (active){
        xs[ln][h+0]=r[0]; xs[ln][h+1]=r[1]; xs[ln][h+2]=r[2]; xs[ln][h+3]=r[3];
      }
      __syncthreads();
      if (tid < 128){
        int n2 = tid >> 4, c = tid & 15;
        int node = vb*8 + n2;
        if (node < N){
          float acc = ab[c];
          #pragma unroll 4
          for (int k = 0; k < H; k++)
            acc = fmaf(xs[n2][k], aw[k*C + c], acc);
          escore[(size_t)node*C + c] = __expf(acc);
        }
      }
      __syncthreads();   // xs reuse across grid-stride iterations
    }
  }
}

// partial[g][b][c][h] = strided-node partial of escore[n][c]*x[n][h]
__global__ __launch_bounds__(256) void k_clust(const u16* __restrict__ xb,
    const float* __restrict__ escore, const int* __restrict__ gs,
    float* __restrict__ partial){
  int g = blockIdx.x >> 4, b = blockIdx.x & 15;
  int h = threadIdx.x & 127, cg = threadIdx.x >> 7;
  int a = gs[g], e2 = gs[g+1];
  float acc[8] = {0,0,0,0,0,0,0,0};
  for (int n = a + b; n < e2; n += 16){
    float xv = bf2f(xb[(size_t)n*H + h]);
    const float4* ep = (const float4*)(escore + (size_t)n*C) + cg*2;
    float4 e0 = ep[0], e1 = ep[1];
    acc[0] = fmaf(e0.x, xv, acc[0]);
    acc[1] = fmaf(e0.y, xv, acc[1]);
    acc[2] = fmaf(e0.z, xv, acc[2]);
    acc[3] = fmaf(e0.w, xv, acc[3]);
    acc[4] = fmaf(e1.x, xv, acc[4]);
    acc[5] = fmaf(e1.y, xv, acc[5]);
    acc[6] = fmaf(e1.z, xv, acc[6]);
    acc[7] = fmaf(e1.w, xv, acc[7]);
  }
  int c0 = cg*8;
  float* dst = partial + (((size_t)(g*16 + b))*C)*H + h;
  #pragma unroll
  for (int r = 0; r < 8; r++)
    dst[(size_t)(c0 + r)*H] = acc[r];
}

// k_out with fused denom (sum of escore over the graph's nodes per cluster)
__global__ __launch_bounds__(256) void k_out(const float* __restrict__ partial,
    const float* __restrict__ escore, const int* __restrict__ gs,
    const float* __restrict__ out_W, const float* __restrict__ out_b,
    float* __restrict__ out){
  __shared__ float cs[2][128];
  __shared__ float dsum[4];
  int tid = threadIdx.x;
  int r = tid >> 7, h = tid & 127;
  int row = blockIdx.x*2 + r;          // (g,c) flat
  int g = row >> 4, c = row & 15;
  int a = gs[g], b2 = gs[g+1];
  // denom
  float s = 0.f;
  for (int n = a + h; n < b2; n += 128) s += escore[(size_t)n*C + c];
  s += __shfl_xor(s, 1, 64);  s += __shfl_xor(s, 2, 64);
  s += __shfl_xor(s, 4, 64);  s += __shfl_xor(s, 8, 64);
  s += __shfl_xor(s, 16, 64); s += __shfl_xor(s, 32, 64);
  if ((tid & 63) == 0) dsum[tid >> 6] = s;
  // cluster sum reduce
  float p = 0.f;
  for (int b = 0; b < 16; b++)
    p += partial[(((size_t)(g*16 + b))*C + c)*H + h];
  cs[r][h] = p;
  __syncthreads();
  float gden = dsum[r*2] + dsum[r*2 + 1];
  float inv = gden > 0.f ? 1.0f / gden : 0.f;
  float acc = 0.f;
  for (int hh = 0; hh < H; hh++)
    acc = fmaf(cs[r][hh], out_W[hh*ODIM + h], acc);
  out[(size_t)row*ODIM + h] = fmaf(acc, inv, out_b[h]);
}

// ---------------- host ----------------
extern "C" void kernel_launch(void* const* d_in, const int* in_sizes, int n_in,
                              void* d_out, int out_size, void* d_ws, size_t ws_size,
                              hipStream_t stream){
  const float* emb    = (const float*)d_in[0];
  const float* Wl     = (const float*)d_in[1];
  const float* bl     = (const float*)d_in[2];
  const float* Wr     = (const float*)d_in[3];
  const float* gamma  = (const float*)d_in[4];
  const float* beta   = (const float*)d_in[5];
  const float* attn_W = (const float*)d_in[6];
  const float* attn_b = (const float*)d_in[7];
  const float* out_W  = (const float*)d_in[8];
  const float* out_b  = (const float*)d_in[9];
  const int* deg    = (const int*)d_in[10];
  const int* ei     = (const int*)d_in[11];
  const int* batch  = (const int*)d_in[12];
  float* out = (float*)d_out;

  const int N = in_sizes[10];
  const int E = in_sizes[11] / 2;
  const int L = in_sizes[1] / (H*H);
  const int B = out_size / (C*ODIM);
  const int NB = (N + 127) >> 7;        // buckets of 128 nodes
  const int nbh = NB * NP;              // blkhist elements
  const int chunk = (E + NP - 1) / NP;  // edges per hist/place block
  const int nblkL = (N + 63) / 64;      // k_linear grid

  size_t off = 0;
  auto alloc = [&](size_t bytes) -> void* {
    void* p = (char*)d_ws + off;
    off += (bytes + 255) & ~(size_t)255;
    return p;
  };
  u16*   xb     = (u16*)  alloc((size_t)N*H*2);
  u32*   xq     = (u32*)  alloc((size_t)N*H);    // fp8 shadow of xb
  u16*   meanb  = (u16*)  alloc((size_t)N*H*2);
  u16*   x2b    = (u16*)  alloc((size_t)N*H*2);
  int2*  pairs  = (int2*) alloc((size_t)E*8);
  float* partial= (float*)alloc((size_t)B*16*C*H*4);  // dedicated (8.4 MB)
  u16*   Wt     = (u16*)  alloc((size_t)L*H*256*2);
  float* escore = (float*)alloc((size_t)N*C*4);
  int*   col    = (int*)  alloc((size_t)E*4);
  int*   rowptr = (int*)  alloc((size_t)(N+1)*4);
  int*   blkhist= (int*)  alloc((size_t)nbh*4);
  int*   bases  = (int*)  alloc((size_t)nbh*4);
  int*   bsum   = (int*)  alloc(256*4);
  int*   gs     = (int*)  alloc((size_t)(B+1)*4);
  float* statsh = (float*)alloc((size_t)L*NSH*256*4);  // stat shards

  // fused setup (grid-strided over virtual blocks)
  int gz = L*NSH;                       // shard-zero blocks
  int g0 = gz + (N*32 + 255)/256;       // + embed
  int g1 = g0 + (N + 255)/256;          // + bounds
  int g2 = g1 + L*16;                   // + wprep
  int gT = g2 + NP;                     // + hist
  hipLaunchKernelGGL(k_setup, dim3(min(gT, GSB)), dim3(256), 0, stream,
                     emb, deg, xb, xq, batch, gs, Wl, Wr, Wt, ei, blkhist,
                     statsh, N, B, NB, E, chunk, gz, g0, g1, g2, gT);
  int nblkS = (nbh + 1023) / 1024;
  hipLaunchKernelGGL(k_scanA, dim3(nblkS), dim3(256), 0, stream, blkhist, bases, bsum, nbh);
  hipLaunchKernelGGL(k_place, dim3(NP), dim3(256), 0, stream,
                     ei, bases, bsum, pairs, NB, E, chunk, nblkS);
  hipLaunchKernelGGL(k_cnt_place, dim3(NB), dim3(256), 0, stream,
                     pairs, bases, bsum, rowptr, col, NB, N, E, nblkS);

  float invN = 1.0f / (float)N;
  int nvb = (N*32 + 255)/256;
  for (int l = 0; l < L; l++){
    float* sh_l = statsh + (size_t)l*NSH*256;
    hipLaunchKernelGGL(k_agg,    dim3(min((N+3)/4, GSB)), dim3(256), 0, stream,
                       xq, rowptr, col, meanb, N);
    hipLaunchKernelGGL(k_linear, dim3(nblkL),    dim3(256), 0, stream,
                       meanb, xb, Wt + (size_t)l*H*256, bl + (size_t)l*H, x2b,
                       sh_l, N);
    hipLaunchKernelGGL(k_bnrelu, dim3(min(nvb, GSB)), dim3(256), 0, stream,
                       x2b, sh_l, gamma + (size_t)l*H, beta + (size_t)l*H,
                       xb, xq, N, invN, attn_W, attn_b, escore, (l == L-1) ? 1 : 0);
  }
  hipLaunchKernelGGL(k_clust, dim3(B*16),  dim3(256), 0, stream, xb, escore, gs, partial);
  hipLaunchKernelGGL(k_out,   dim3(B*C/2), dim3(256), 0, stream,
                     partial, escore, gs, out_W, out_b, out);
}

// Round 6
// 323.970 us; speedup vs baseline: 1.0927x; 1.0527x over previous
//
#include <hip/hip_runtime.h>

typedef unsigned short u16;
typedef unsigned int   u32;

#define H    128
#define C    16
#define ODIM 128

typedef short bf16x8 __attribute__((ext_vector_type(8)));
typedef float f32x4  __attribute__((ext_vector_type(4)));
typedef float f32x2v __attribute__((ext_vector_type(2)));

#define WSP 272   // Ws row stride (u16)
#define NP  256   // CSR partitions
#define NSH 16    // stat shards
#define EPS 1e-5f

__device__ __forceinline__ float bf2f(u32 v){
  union { u32 i; float f; } t; t.i = v << 16; return t.f;
}
__device__ __forceinline__ u16 f2bf(float f){
  u32 u = __float_as_uint(f);
  u32 r = u + 0x7fffu + ((u >> 16) & 1u);   // RNE
  return (u16)(r >> 16);
}
__device__ __forceinline__ u32 pack2(float a, float b){
  return (u32)f2bf(a) | ((u32)f2bf(b) << 16);
}

// ---------- fused setup: shard-zero | embed | bounds | wprep | hist ----------
__global__ __launch_bounds__(256) void k_setup(const float* __restrict__ emb,
    const int* __restrict__ deg, u16* __restrict__ xb,
    const int* __restrict__ batch, int* __restrict__ gs,
    const float* __restrict__ Wl, const float* __restrict__ Wr,
    u16* __restrict__ Wt, const int* __restrict__ ei,
    int* __restrict__ blkhist, float* __restrict__ statsh,
    int N, int B, int NB, int E, int chunk,
    int gz, int g0, int g1, int g2){
  __shared__ __align__(16) char smem[4608];
  int bid = blockIdx.x, tid = threadIdx.x;
  if (bid < gz){
    statsh[bid*256 + tid] = 0.f;
  } else if (bid < g0){
    // ---- embed (bf16 only; no fp8 shadow) ----
    int i = (bid - gz)*256 + tid;
    if (i < N*32){
      int n = i >> 5, q = i & 31;
      int d = deg[n];
      float4 v = ((const float4*)(emb + (size_t)d*H))[q];
      uint2 o; o.x = pack2(v.x, v.y); o.y = pack2(v.z, v.w);
      ((uint2*)(xb + (size_t)n*H))[q] = o;
    }
  } else if (bid < g1){
    // ---- bounds ----
    int n = (bid - g0)*256 + tid;
    if (n < N){
      int b = batch[n];
      if (n == 0){ for (int g = 0; g <= b; g++) gs[g] = 0; }
      else {
        int pb = batch[n-1];
        for (int g = pb+1; g <= b; g++) gs[g] = n;
      }
      if (n == N-1){ for (int g = b+1; g <= B; g++) gs[g] = N; }
    }
  } else if (bid < g2){
    // ---- wprep: Wt[l][h][k] ----
    u16 (*T)[18] = (u16(*)[18])smem;
    int b = bid - g1;
    int strip = b & 7, half = (b >> 3) & 1, l = b >> 4;
    const float* M = (half ? Wr : Wl) + (size_t)l*H*H;
    int k0 = strip * 16;
    #pragma unroll
    for (int j = 0; j < 8; j++){
      int u = tid + j*256;
      int kk = u >> 7, h = u & 127;
      T[h][kk] = f2bf(M[(size_t)(k0 + kk)*H + h]);
    }
    __syncthreads();
    #pragma unroll
    for (int j = 0; j < 8; j++){
      int u = tid + j*256;
      int h = u >> 4, k16 = u & 15;
      Wt[((size_t)(l*H + h))*256 + half*128 + k0 + k16] = T[h][k16];
    }
  } else {
    // ---- hist ----
    int* hist = (int*)smem;
    int blk = bid - g2;
    for (int b = tid; b < NB; b += 256) hist[b] = 0;
    __syncthreads();
    int start = blk*chunk, end = min(E, start + chunk);
    for (int e = start + tid; e < end; e += 256)
      atomicAdd(&hist[ei[E + e] >> 7], 1);
    __syncthreads();
    for (int b = tid; b < NB; b += 256) blkhist[b*NP + blk] = hist[b];
  }
}

// generic scan over n ints (1024 per block); writes per-block totals to bsum
__global__ __launch_bounds__(256) void k_scanA(const int* __restrict__ in,
    int* __restrict__ out, int* __restrict__ bsum, int n){
  __shared__ int wsum[4];
  int tid = threadIdx.x;
  int base = blockIdx.x*1024 + tid*4;
  int v0 = (base+0 < n) ? in[base+0] : 0;
  int v1 = (base+1 < n) ? in[base+1] : 0;
  int v2 = (base+2 < n) ? in[base+2] : 0;
  int v3 = (base+3 < n) ? in[base+3] : 0;
  int tsum = v0+v1+v2+v3;
  int lane = tid & 63, w = tid >> 6;
  int incl = tsum;
  for (int d = 1; d < 64; d <<= 1){
    int t = __shfl_up(incl, d, 64);
    if (lane >= d) incl += t;
  }
  if (lane == 63) wsum[w] = incl;
  __syncthreads();
  int woff = 0;
  for (int i = 0; i < w; i++) woff += wsum[i];
  int excl = woff + incl - tsum;
  if (base+0 < n) out[base+0] = excl;
  if (base+1 < n) out[base+1] = excl + v0;
  if (base+2 < n) out[base+2] = excl + v0 + v1;
  if (base+3 < n) out[base+3] = excl + v0 + v1 + v2;
  if (tid == 255) bsum[blockIdx.x] = woff + incl;
}

// in-block exclusive scan of bsum[0..nb) -> bo[0..255] (nb <= 256)
__device__ __forceinline__ void scan_bsum(const int* __restrict__ bsum,
    int* bo, int nb, int tid){
  __shared__ int ws2[4];
  int v = (tid < nb) ? bsum[tid] : 0;
  int lane = tid & 63, w = tid >> 6;
  int incl = v;
  for (int d = 1; d < 64; d <<= 1){
    int t = __shfl_up(incl, d, 64);
    if (lane >= d) incl += t;
  }
  if (lane == 63) ws2[w] = incl;
  __syncthreads();
  int woff = 0;
  for (int i = 0; i < w; i++) woff += ws2[i];
  bo[tid] = woff + incl - v;
  __syncthreads();
}

// place edges bucket-sorted as (src,dst) pairs; boff computed locally
__global__ __launch_bounds__(256) void k_place(const int* __restrict__ ei,
    const int* __restrict__ bases, const int* __restrict__ bsum,
    int2* __restrict__ pairs, int NB, int E, int chunk, int nbs){
  __shared__ int cursor[400];
  __shared__ int bo[256];
  int blk = blockIdx.x, tid = threadIdx.x;
  scan_bsum(bsum, bo, nbs, tid);
  for (int b = tid; b < NB; b += 256){
    int i = b*NP + blk;
    cursor[b] = bases[i] + bo[i >> 10];
  }
  __syncthreads();
  int start = blk*chunk, end = min(E, start + chunk);
  for (int e = start + tid; e < end; e += 256){
    int s = ei[e], d = ei[E + e];
    int pos = atomicAdd(&cursor[d >> 7], 1);
    pairs[pos] = make_int2(s, d);
  }
}

// per bucket: per-node counts -> rowptr (direct), then node-sort col
__global__ __launch_bounds__(256) void k_cnt_place(const int2* __restrict__ pairs,
    const int* __restrict__ bases, const int* __restrict__ bsum,
    int* __restrict__ rowptr, int* __restrict__ col,
    int NB, int N, int E, int nbs){
  int b = blockIdx.x, tid = threadIdx.x;
  __shared__ int bo[256];
  scan_bsum(bsum, bo, nbs, tid);
  int i0 = b*NP;
  int bstart = bases[i0] + bo[i0 >> 10];
  int bend = E;
  if (b+1 < NB){ int i1 = (b+1)*NP; bend = bases[i1] + bo[i1 >> 10]; }
  __shared__ int cnt[128], sc[128], rank[128];
  if (tid < 128) cnt[tid] = 0;
  __syncthreads();
  for (int e = bstart + tid; e < bend; e += 256)
    atomicAdd(&cnt[pairs[e].y & 127], 1);
  __syncthreads();
  if (tid < 128) sc[tid] = cnt[tid];
  for (int d = 1; d < 128; d <<= 1){
    int v = 0;
    __syncthreads();
    if (tid < 128 && tid >= d) v = sc[tid - d];
    __syncthreads();
    if (tid < 128) sc[tid] += v;
  }
  __syncthreads();
  if (tid < 128){
    int excl = sc[tid] - cnt[tid];
    rank[tid] = bstart + excl;
    int node = b*128 + tid;
    if (node < N) rowptr[node] = bstart + excl;
  }
  if (b == NB-1 && tid == 0) rowptr[N] = E;
  __syncthreads();
  for (int e = bstart + tid; e < bend; e += 256){
    int2 p = pairs[e];
    int pos = atomicAdd(&rank[p.y & 127], 1);
    col[pos] = p.x;
  }
}

// ---------------- per-layer ----------------
// k_agg: wave per node, 16 lanes x uint4 (8 bf16 feats) per gathered row,
// 4 edge-groups, 2-deep unroll (16 cache lines in flight / wave).
// DO_BN: apply y = max(v*sc + bo, 0) per edge (BN+ReLU folded into decode).
template<int DO_BN>
__device__ __forceinline__ void dec8bn(f32x2v* a, const f32x2v* scp,
    const f32x2v* bop, uint4 v){
  u32 ws[4] = {v.x, v.y, v.z, v.w};
  #pragma unroll
  for (int j = 0; j < 4; j++){
    f32x2v d = { bf2f(ws[j] & 0xffffu), bf2f(ws[j] >> 16) };
    if (DO_BN){
      d = d * scp[j] + bop[j];
      d.x = fmaxf(d.x, 0.f); d.y = fmaxf(d.y, 0.f);
    }
    a[j] += d;
  }
}

template<int DO_BN>
__global__ __launch_bounds__(256) void k_agg(const u16* __restrict__ xsrc,
    const int* __restrict__ rowptr, const int* __restrict__ col,
    u16* __restrict__ meanb, const float* __restrict__ statsh_p,
    const float* __restrict__ gamma_p, const float* __restrict__ beta_p,
    float invN, int N){
  __shared__ float scb[256];   // sc[0..127], bo[128..255]
  int tid = threadIdx.x;
  if (DO_BN){
    __shared__ float st[256];
    float sacc = 0.f;
    #pragma unroll
    for (int s2 = 0; s2 < NSH; s2++) sacc += statsh_p[s2*256 + tid];
    st[tid] = sacc;
    __syncthreads();
    if (tid < 128){
      float mu  = st[tid] * invN;
      float var = fmaf(-mu, mu, st[128 + tid] * invN);
      float s   = rsqrtf(var + EPS) * gamma_p[tid];
      scb[tid]       = s;
      scb[128 + tid] = beta_p[tid] - mu * s;
    }
    __syncthreads();
  }
  int wid  = (blockIdx.x*256 + tid) >> 6;
  if (wid >= N) return;
  int lane = tid & 63;
  int grp = lane >> 4, fl = lane & 15;   // 4 groups x 16 lanes
  f32x2v scp[4], bop[4];
  if (DO_BN){
    #pragma unroll
    for (int j = 0; j < 4; j++){
      scp[j] = (f32x2v){ scb[fl*8 + 2*j],       scb[fl*8 + 2*j + 1] };
      bop[j] = (f32x2v){ scb[128 + fl*8 + 2*j], scb[128 + fl*8 + 2*j + 1] };
    }
  }
  const u16* xf = xsrc + fl*8;          // 8 bf16 features per lane
  int r0 = rowptr[wid], r1 = rowptr[wid+1];
  f32x2v a[4];
  #pragma unroll
  for (int j = 0; j < 4; j++) a[j] = (f32x2v){0.f, 0.f};
  int e = r0 + grp;
  for (; e + 4 < r1; e += 8){
    uint4 v = *(const uint4*)(xf + (size_t)col[e]*H);
    uint4 u = *(const uint4*)(xf + (size_t)col[e+4]*H);
    dec8bn<DO_BN>(a, scp, bop, v);
    dec8bn<DO_BN>(a, scp, bop, u);
  }
  if (e < r1){
    uint4 v = *(const uint4*)(xf + (size_t)col[e]*H);
    dec8bn<DO_BN>(a, scp, bop, v);
  }
  #pragma unroll
  for (int j = 0; j < 4; j++){
    a[j].x += __shfl_xor(a[j].x, 16, 64); a[j].y += __shfl_xor(a[j].y, 16, 64);
    a[j].x += __shfl_xor(a[j].x, 32, 64); a[j].y += __shfl_xor(a[j].y, 32, 64);
  }
  if (grp == 0){
    float invc = 1.0f / (float)max(r1 - r0, 1);
    uint4 o;
    o.x = pack2(a[0].x*invc, a[0].y*invc);
    o.y = pack2(a[1].x*invc, a[1].y*invc);
    o.z = pack2(a[2].x*invc, a[2].y*invc);
    o.w = pack2(a[3].x*invc, a[3].y*invc);
    *(uint4*)(meanb + (size_t)wid*H + fl*8) = o;
  }
}

// x2b_out[n][h] (bf16, PRE-BN) = bl[h] + [meanb | bn(xsrc)] @ Wt^T.
// DO_BN: x-side A-fragments get BN+ReLU applied in-register (stats_prev).
template<int DO_BN>
__global__ __launch_bounds__(256) void k_linear(const u16* __restrict__ meanb,
    const u16* __restrict__ xsrc, const u16* __restrict__ Wt,
    const float* __restrict__ bl, u16* __restrict__ x2b,
    float* __restrict__ statsh_l, const float* __restrict__ statsh_p,
    const float* __restrict__ gamma_p, const float* __restrict__ beta_p,
    float invN, int N){
  __shared__ u16 Ws[128][WSP];         // 69.6 KB -> 2 blocks/CU
  __shared__ float Sh[128], Qh[128];
  __shared__ float st[256];
  __shared__ float scl[128], bol[128];
  int tid = threadIdx.x;
  if (tid < 128){ Sh[tid] = 0.f; Qh[tid] = 0.f; }
  int lane = tid & 63, w = tid >> 6;
  int mlane = lane & 15, quad = lane >> 4;
  int node = blockIdx.x*64 + w*16 + mlane;
  const u16* arow_m = meanb + (size_t)node*H + quad*8;
  const u16* arow_x = xsrc + (size_t)node*H + quad*8;
  bf16x8 af[8];
  #pragma unroll
  for (int kk = 0; kk < 4; kk++){
    af[kk]     = *(const bf16x8*)(arow_m + kk*32);
    af[kk + 4] = *(const bf16x8*)(arow_x + kk*32);
  }
  #pragma unroll
  for (int j = 0; j < 16; j++){
    int u = tid + j*256;
    int row = u >> 5, seg = u & 31;
    uint4 v = ((const uint4*)(Wt + (size_t)row*256))[seg];
    *(uint4*)&Ws[row][seg*8] = v;
  }
  if (DO_BN){
    float sacc = 0.f;
    #pragma unroll
    for (int s2 = 0; s2 < NSH; s2++) sacc += statsh_p[s2*256 + tid];
    st[tid] = sacc;
  }
  __syncthreads();
  if (DO_BN){
    if (tid < 128){
      float mu  = st[tid] * invN;
      float var = fmaf(-mu, mu, st[128 + tid] * invN);
      float s   = rsqrtf(var + EPS) * gamma_p[tid];
      scl[tid] = s;
      bol[tid] = beta_p[tid] - mu * s;
    }
    __syncthreads();
    // BN+ReLU on x-side fragments (h = kk*32 + quad*8 + j, uniform per quad)
    #pragma unroll
    for (int kk = 0; kk < 4; kk++){
      bf16x8 raw = af[kk + 4];
      bf16x8 outv;
      #pragma unroll
      for (int j = 0; j < 8; j++){
        int h = kk*32 + quad*8 + j;
        float d = bf2f((u32)(u16)raw[j]);
        float y = fmaxf(fmaf(d, scl[h], bol[h]), 0.f);
        outv[j] = (short)f2bf(y);
      }
      af[kk + 4] = outv;
    }
  }
  f32x4 acc[8];
  #pragma unroll
  for (int t = 0; t < 8; t++) acc[t] = (f32x4){0.f, 0.f, 0.f, 0.f};
  #pragma unroll
  for (int kk = 0; kk < 8; kk++){
    #pragma unroll
    for (int t = 0; t < 8; t++){
      bf16x8 b = *(const bf16x8*)&Ws[t*16 + mlane][kk*32 + quad*8];
      acc[t] = __builtin_amdgcn_mfma_f32_16x16x32_bf16(af[kk], b, acc[t], 0, 0, 0);
    }
  }
  #pragma unroll
  for (int t = 0; t < 8; t++){
    int h = t*16 + mlane;
    float bv = bl[h];
    float s = 0.f, q = 0.f;
    #pragma unroll
    for (int r = 0; r < 4; r++){
      int nd = blockIdx.x*64 + w*16 + quad*4 + r;
      if (nd < N){
        float v = acc[t][r] + bv;
        x2b[(size_t)nd*H + h] = f2bf(v);
        s += v; q = fmaf(v, v, q);
      }
    }
    s += __shfl_xor(s, 16, 64); s += __shfl_xor(s, 32, 64);
    q += __shfl_xor(q, 16, 64); q += __shfl_xor(q, 32, 64);
    if (quad == 0){
      atomicAdd(&Sh[h], s);
      atomicAdd(&Qh[h], q);
    }
  }
  __syncthreads();
  {
    float v = (tid < 128) ? Sh[tid] : Qh[tid - 128];
    atomicAdd(&statsh_l[(blockIdx.x & (NSH-1))*256 + tid], v);
  }
}

// final BN+ReLU: reads bf16 x2b + last-layer stats, writes xb_final and
// fused attention scores (always do_scores).
__global__ __launch_bounds__(256) void k_bnrelu(const u16* __restrict__ x2b,
    const float* __restrict__ statsh_l, const float* __restrict__ gamma,
    const float* __restrict__ beta, u16* __restrict__ xb,
    int N, float invN,
    const float* __restrict__ attn_W, const float* __restrict__ attn_b,
    float* __restrict__ escore){
  __shared__ float st[256];
  __shared__ float xs[8][132];
  __shared__ float aw[H*C];
  __shared__ float ab[C];
  int tid = threadIdx.x;
  {
    float sacc = 0.f;
    #pragma unroll
    for (int s2 = 0; s2 < NSH; s2++) sacc += statsh_l[s2*256 + tid];
    st[tid] = sacc;
  }
  #pragma unroll
  for (int j = 0; j < 8; j++) aw[tid + j*256] = attn_W[tid + j*256];
  if (tid < C) ab[tid] = attn_b[tid];
  __syncthreads();
  int i = blockIdx.x*256 + tid;
  bool active = (i < N*32);
  int h = (tid & 31) * 4;
  float r[4] = {0.f, 0.f, 0.f, 0.f};
  if (active){
    uint2 o2 = ((const uint2*)x2b)[i];
    float vv[4] = {bf2f(o2.x & 0xffff), bf2f(o2.x >> 16),
                   bf2f(o2.y & 0xffff), bf2f(o2.y >> 16)};
    #pragma unroll
    for (int j = 0; j < 4; j++){
      float mu  = st[h+j] * invN;
      float var = fmaf(-mu, mu, st[H + h + j] * invN);
      float sc  = rsqrtf(var + EPS) * gamma[h+j];
      float bi  = beta[h+j];
      r[j] = fmaxf(fmaf(vv[j] - mu, sc, bi), 0.0f);
    }
    uint2 o; o.x = pack2(r[0], r[1]); o.y = pack2(r[2], r[3]);
    ((uint2*)xb)[i] = o;
  }
  {
    int ln = tid >> 5;
    if (active){
      xs[ln][h+0]=r[0]; xs[ln][h+1]=r[1]; xs[ln][h+2]=r[2]; xs[ln][h+3]=r[3];
    }
    __syncthreads();
    if (tid < 128){
      int n2 = tid >> 4, c = tid & 15;
      int node = blockIdx.x*8 + n2;
      if (node < N){
        float acc = ab[c];
        #pragma unroll 4
        for (int k = 0; k < H; k++)
          acc = fmaf(xs[n2][k], aw[k*C + c], acc);
        escore[(size_t)node*C + c] = __expf(acc);
      }
    }
  }
}

// partial[g][b][c][h] = strided-node partial of escore[n][c]*x[n][h]
__global__ __launch_bounds__(256) void k_clust(const u16* __restrict__ xb,
    const float* __restrict__ escore, const int* __restrict__ gs,
    float* __restrict__ partial){
  int g = blockIdx.x >> 4, b = blockIdx.x & 15;
  int h = threadIdx.x & 127, cg = threadIdx.x >> 7;
  int a = gs[g], e2 = gs[g+1];
  float acc[8] = {0,0,0,0,0,0,0,0};
  for (int n = a + b; n < e2; n += 16){
    float xv = bf2f(xb[(size_t)n*H + h]);
    const float4* ep = (const float4*)(escore + (size_t)n*C) + cg*2;
    float4 e0 = ep[0], e1 = ep[1];
    acc[0] = fmaf(e0.x, xv, acc[0]);
    acc[1] = fmaf(e0.y, xv, acc[1]);
    acc[2] = fmaf(e0.z, xv, acc[2]);
    acc[3] = fmaf(e0.w, xv, acc[3]);
    acc[4] = fmaf(e1.x, xv, acc[4]);
    acc[5] = fmaf(e1.y, xv, acc[5]);
    acc[6] = fmaf(e1.z, xv, acc[6]);
    acc[7] = fmaf(e1.w, xv, acc[7]);
  }
  int c0 = cg*8;
  float* dst = partial + (((size_t)(g*16 + b))*C)*H + h;
  #pragma unroll
  for (int r = 0; r < 8; r++)
    dst[(size_t)(c0 + r)*H] = acc[r];
}

// k_out with fused denom (sum of escore over the graph's nodes per cluster)
__global__ __launch_bounds__(256) void k_out(const float* __restrict__ partial,
    const float* __restrict__ escore, const int* __restrict__ gs,
    const float* __restrict__ out_W, const float* __restrict__ out_b,
    float* __restrict__ out){
  __shared__ float cs[2][128];
  __shared__ float dsum[4];
  int tid = threadIdx.x;
  int r = tid >> 7, h = tid & 127;
  int row = blockIdx.x*2 + r;          // (g,c) flat
  int g = row >> 4, c = row & 15;
  int a = gs[g], b2 = gs[g+1];
  // denom
  float s = 0.f;
  for (int n = a + h; n < b2; n += 128) s += escore[(size_t)n*C + c];
  s += __shfl_xor(s, 1, 64);  s += __shfl_xor(s, 2, 64);
  s += __shfl_xor(s, 4, 64);  s += __shfl_xor(s, 8, 64);
  s += __shfl_xor(s, 16, 64); s += __shfl_xor(s, 32, 64);
  if ((tid & 63) == 0) dsum[tid >> 6] = s;
  // cluster sum reduce
  float p = 0.f;
  for (int b = 0; b < 16; b++)
    p += partial[(((size_t)(g*16 + b))*C + c)*H + h];
  cs[r][h] = p;
  __syncthreads();
  float gden = dsum[r*2] + dsum[r*2 + 1];
  float inv = gden > 0.f ? 1.0f / gden : 0.f;
  float acc = 0.f;
  for (int hh = 0; hh < H; hh++)
    acc = fmaf(cs[r][hh], out_W[hh*ODIM + h], acc);
  out[(size_t)row*ODIM + h] = fmaf(acc, inv, out_b[h]);
}

// ---------------- host ----------------
extern "C" void kernel_launch(void* const* d_in, const int* in_sizes, int n_in,
                              void* d_out, int out_size, void* d_ws, size_t ws_size,
                              hipStream_t stream){
  const float* emb    = (const float*)d_in[0];
  const float* Wl     = (const float*)d_in[1];
  const float* bl     = (const float*)d_in[2];
  const float* Wr     = (const float*)d_in[3];
  const float* gamma  = (const float*)d_in[4];
  const float* beta   = (const float*)d_in[5];
  const float* attn_W = (const float*)d_in[6];
  const float* attn_b = (const float*)d_in[7];
  const float* out_W  = (const float*)d_in[8];
  const float* out_b  = (const float*)d_in[9];
  const int* deg    = (const int*)d_in[10];
  const int* ei     = (const int*)d_in[11];
  const int* batch  = (const int*)d_in[12];
  float* out = (float*)d_out;

  const int N = in_sizes[10];
  const int E = in_sizes[11] / 2;
  const int L = in_sizes[1] / (H*H);
  const int B = out_size / (C*ODIM);
  const int NB = (N + 127) >> 7;        // buckets of 128 nodes
  const int nbh = NB * NP;              // blkhist elements
  const int chunk = (E + NP - 1) / NP;  // edges per hist/place block
  const int nblkL = (N + 63) / 64;      // k_linear grid

  size_t off = 0;
  auto alloc = [&](size_t bytes) -> void* {
    void* p = (char*)d_ws + off;
    off += (bytes + 255) & ~(size_t)255;
    return p;
  };
  u16*   xb     = (u16*)  alloc((size_t)N*H*2);       // emb in, final out
  u16*   x2bA   = (u16*)  alloc((size_t)N*H*2);       // ping
  u16*   x2bB   = (u16*)  alloc((size_t)N*H*2);       // pong
  u16*   meanb  = (u16*)  alloc((size_t)N*H*2);
  int2*  pairs  = (int2*) alloc((size_t)E*8);
  float* partial= (float*)alloc((size_t)B*16*C*H*4);
  u16*   Wt     = (u16*)  alloc((size_t)L*H*256*2);
  float* escore = (float*)alloc((size_t)N*C*4);
  int*   col    = (int*)  alloc((size_t)E*4);
  int*   rowptr = (int*)  alloc((size_t)(N+1)*4);
  int*   blkhist= (int*)  alloc((size_t)nbh*4);
  int*   bases  = (int*)  alloc((size_t)nbh*4);
  int*   bsum   = (int*)  alloc(256*4);
  int*   gs     = (int*)  alloc((size_t)(B+1)*4);
  float* statsh = (float*)alloc((size_t)L*NSH*256*4);

  // fused setup
  int gz = L*NSH;
  int g0 = gz + (N*32 + 255)/256;
  int g1 = g0 + (N + 255)/256;
  int g2 = g1 + L*16;
  int gT = g2 + NP;
  hipLaunchKernelGGL(k_setup, dim3(gT), dim3(256), 0, stream,
                     emb, deg, xb, batch, gs, Wl, Wr, Wt, ei, blkhist,
                     statsh, N, B, NB, E, chunk, gz, g0, g1, g2);
  int nblkS = (nbh + 1023) / 1024;
  hipLaunchKernelGGL(k_scanA, dim3(nblkS), dim3(256), 0, stream, blkhist, bases, bsum, nbh);
  hipLaunchKernelGGL(k_place, dim3(NP), dim3(256), 0, stream,
                     ei, bases, bsum, pairs, NB, E, chunk, nblkS);
  hipLaunchKernelGGL(k_cnt_place, dim3(NB), dim3(256), 0, stream,
                     pairs, bases, bsum, rowptr, col, NB, N, E, nblkS);

  float invN = 1.0f / (float)N;
  u16* x2buf[2] = {x2bA, x2bB};
  int nblkA = (N + 3) / 4;
  for (int l = 0; l < L; l++){
    const u16* src = (l == 0) ? xb : x2buf[(l-1) & 1];
    u16* dst = x2buf[l & 1];
    float* sh_l = statsh + (size_t)l*NSH*256;
    const float* sh_p = (l == 0) ? nullptr : statsh + (size_t)(l-1)*NSH*256;
    const float* gp = gamma + (size_t)(l-1)*H;
    const float* bp = beta  + (size_t)(l-1)*H;
    if (l == 0){
      k_agg<0><<<dim3(nblkA), dim3(256), 0, stream>>>(
          src, rowptr, col, meanb, nullptr, nullptr, nullptr, invN, N);
      k_linear<0><<<dim3(nblkL), dim3(256), 0, stream>>>(
          meanb, src, Wt + (size_t)l*H*256, bl + (size_t)l*H, dst,
          sh_l, nullptr, nullptr, nullptr, invN, N);
    } else {
      k_agg<1><<<dim3(nblkA), dim3(256), 0, stream>>>(
          src, rowptr, col, meanb, sh_p, gp, bp, invN, N);
      k_linear<1><<<dim3(nblkL), dim3(256), 0, stream>>>(
          meanb, src, Wt + (size_t)l*H*256, bl + (size_t)l*H, dst,
          sh_l, sh_p, gp, bp, invN, N);
    }
  }
  hipLaunchKernelGGL(k_bnrelu, dim3((N*32+255)/256), dim3(256), 0, stream,
                     x2buf[(L-1) & 1], statsh + (size_t)(L-1)*NSH*256,
                     gamma + (size_t)(L-1)*H, beta + (size_t)(L-1)*H,
                     xb, N, invN, attn_W, attn_b, escore);
  hipLaunchKernelGGL(k_clust, dim3(B*16),  dim3(256), 0, stream, xb, escore, gs, partial);
  hipLaunchKernelGGL(k_out,   dim3(B*C/2), dim3(256), 0, stream,
                     partial, escore, gs, out_W, out_b, out);
}

// Round 7
// 313.566 us; speedup vs baseline: 1.1289x; 1.0332x over previous
//
#include <hip/hip_runtime.h>

typedef unsigned short u16;
typedef unsigned int   u32;

#define H    128
#define C    16
#define ODIM 128

typedef short bf16x8 __attribute__((ext_vector_type(8)));
typedef float f32x4  __attribute__((ext_vector_type(4)));
typedef float f32x2v __attribute__((ext_vector_type(2)));

#define WSP 272   // Ws row stride (u16)
#define NP  256   // CSR partitions
#define NSH 16    // stat shards
#define EPS 1e-5f

__device__ __forceinline__ float bf2f(u32 v){
  union { u32 i; float f; } t; t.i = v << 16; return t.f;
}
__device__ __forceinline__ u16 f2bf(float f){
  u32 u = __float_as_uint(f);
  u32 r = u + 0x7fffu + ((u >> 16) & 1u);   // RNE
  return (u16)(r >> 16);
}
__device__ __forceinline__ u32 pack2(float a, float b){
  return (u32)f2bf(a) | ((u32)f2bf(b) << 16);
}

// ---------- fused setup: shard-zero | embed | bounds | wprep | hist ----------
__global__ __launch_bounds__(256) void k_setup(const float* __restrict__ emb,
    const int* __restrict__ deg, u16* __restrict__ xb,
    const int* __restrict__ batch, int* __restrict__ gs,
    const float* __restrict__ Wl, const float* __restrict__ Wr,
    u16* __restrict__ Wt, const int* __restrict__ ei,
    int* __restrict__ blkhist, float* __restrict__ statsh,
    int N, int B, int NB, int E, int chunk,
    int gz, int g0, int g1, int g2){
  __shared__ __align__(16) char smem[4608];
  int bid = blockIdx.x, tid = threadIdx.x;
  if (bid < gz){
    statsh[bid*256 + tid] = 0.f;
  } else if (bid < g0){
    // ---- embed (bf16 only) ----
    int i = (bid - gz)*256 + tid;
    if (i < N*32){
      int n = i >> 5, q = i & 31;
      int d = deg[n];
      float4 v = ((const float4*)(emb + (size_t)d*H))[q];
      uint2 o; o.x = pack2(v.x, v.y); o.y = pack2(v.z, v.w);
      ((uint2*)(xb + (size_t)n*H))[q] = o;
    }
  } else if (bid < g1){
    // ---- bounds ----
    int n = (bid - g0)*256 + tid;
    if (n < N){
      int b = batch[n];
      if (n == 0){ for (int g = 0; g <= b; g++) gs[g] = 0; }
      else {
        int pb = batch[n-1];
        for (int g = pb+1; g <= b; g++) gs[g] = n;
      }
      if (n == N-1){ for (int g = b+1; g <= B; g++) gs[g] = N; }
    }
  } else if (bid < g2){
    // ---- wprep: Wt[l][h][k] ----
    u16 (*T)[18] = (u16(*)[18])smem;
    int b = bid - g1;
    int strip = b & 7, half = (b >> 3) & 1, l = b >> 4;
    const float* M = (half ? Wr : Wl) + (size_t)l*H*H;
    int k0 = strip * 16;
    #pragma unroll
    for (int j = 0; j < 8; j++){
      int u = tid + j*256;
      int kk = u >> 7, h = u & 127;
      T[h][kk] = f2bf(M[(size_t)(k0 + kk)*H + h]);
    }
    __syncthreads();
    #pragma unroll
    for (int j = 0; j < 8; j++){
      int u = tid + j*256;
      int h = u >> 4, k16 = u & 15;
      Wt[((size_t)(l*H + h))*256 + half*128 + k0 + k16] = T[h][k16];
    }
  } else {
    // ---- hist ----
    int* hist = (int*)smem;
    int blk = bid - g2;
    for (int b = tid; b < NB; b += 256) hist[b] = 0;
    __syncthreads();
    int start = blk*chunk, end = min(E, start + chunk);
    for (int e = start + tid; e < end; e += 256)
      atomicAdd(&hist[ei[E + e] >> 7], 1);
    __syncthreads();
    for (int b = tid; b < NB; b += 256) blkhist[b*NP + blk] = hist[b];
  }
}

// generic scan over n ints (1024 per block); writes per-block totals to bsum
__global__ __launch_bounds__(256) void k_scanA(const int* __restrict__ in,
    int* __restrict__ out, int* __restrict__ bsum, int n){
  __shared__ int wsum[4];
  int tid = threadIdx.x;
  int base = blockIdx.x*1024 + tid*4;
  int v0 = (base+0 < n) ? in[base+0] : 0;
  int v1 = (base+1 < n) ? in[base+1] : 0;
  int v2 = (base+2 < n) ? in[base+2] : 0;
  int v3 = (base+3 < n) ? in[base+3] : 0;
  int tsum = v0+v1+v2+v3;
  int lane = tid & 63, w = tid >> 6;
  int incl = tsum;
  for (int d = 1; d < 64; d <<= 1){
    int t = __shfl_up(incl, d, 64);
    if (lane >= d) incl += t;
  }
  if (lane == 63) wsum[w] = incl;
  __syncthreads();
  int woff = 0;
  for (int i = 0; i < w; i++) woff += wsum[i];
  int excl = woff + incl - tsum;
  if (base+0 < n) out[base+0] = excl;
  if (base+1 < n) out[base+1] = excl + v0;
  if (base+2 < n) out[base+2] = excl + v0 + v1;
  if (base+3 < n) out[base+3] = excl + v0 + v1 + v2;
  if (tid == 255) bsum[blockIdx.x] = woff + incl;
}

// in-block exclusive scan of bsum[0..nb) -> bo[0..255] (nb <= 256)
__device__ __forceinline__ void scan_bsum(const int* __restrict__ bsum,
    int* bo, int nb, int tid){
  __shared__ int ws2[4];
  int v = (tid < nb) ? bsum[tid] : 0;
  int lane = tid & 63, w = tid >> 6;
  int incl = v;
  for (int d = 1; d < 64; d <<= 1){
    int t = __shfl_up(incl, d, 64);
    if (lane >= d) incl += t;
  }
  if (lane == 63) ws2[w] = incl;
  __syncthreads();
  int woff = 0;
  for (int i = 0; i < w; i++) woff += ws2[i];
  bo[tid] = woff + incl - v;
  __syncthreads();
}

// place edges bucket-sorted as (src,dst) pairs; boff computed locally
__global__ __launch_bounds__(256) void k_place(const int* __restrict__ ei,
    const int* __restrict__ bases, const int* __restrict__ bsum,
    int2* __restrict__ pairs, int NB, int E, int chunk, int nbs){
  __shared__ int cursor[400];
  __shared__ int bo[256];
  int blk = blockIdx.x, tid = threadIdx.x;
  scan_bsum(bsum, bo, nbs, tid);
  for (int b = tid; b < NB; b += 256){
    int i = b*NP + blk;
    cursor[b] = bases[i] + bo[i >> 10];
  }
  __syncthreads();
  int start = blk*chunk, end = min(E, start + chunk);
  for (int e = start + tid; e < end; e += 256){
    int s = ei[e], d = ei[E + e];
    int pos = atomicAdd(&cursor[d >> 7], 1);
    pairs[pos] = make_int2(s, d);
  }
}

// per bucket: per-node counts -> rowptr (direct), then node-sort col
__global__ __launch_bounds__(256) void k_cnt_place(const int2* __restrict__ pairs,
    const int* __restrict__ bases, const int* __restrict__ bsum,
    int* __restrict__ rowptr, int* __restrict__ col,
    int NB, int N, int E, int nbs){
  int b = blockIdx.x, tid = threadIdx.x;
  __shared__ int bo[256];
  scan_bsum(bsum, bo, nbs, tid);
  int i0 = b*NP;
  int bstart = bases[i0] + bo[i0 >> 10];
  int bend = E;
  if (b+1 < NB){ int i1 = (b+1)*NP; bend = bases[i1] + bo[i1 >> 10]; }
  __shared__ int cnt[128], sc[128], rank[128];
  if (tid < 128) cnt[tid] = 0;
  __syncthreads();
  for (int e = bstart + tid; e < bend; e += 256)
    atomicAdd(&cnt[pairs[e].y & 127], 1);
  __syncthreads();
  if (tid < 128) sc[tid] = cnt[tid];
  for (int d = 1; d < 128; d <<= 1){
    int v = 0;
    __syncthreads();
    if (tid < 128 && tid >= d) v = sc[tid - d];
    __syncthreads();
    if (tid < 128) sc[tid] += v;
  }
  __syncthreads();
  if (tid < 128){
    int excl = sc[tid] - cnt[tid];
    rank[tid] = bstart + excl;
    int node = b*128 + tid;
    if (node < N) rowptr[node] = bstart + excl;
  }
  if (b == NB-1 && tid == 0) rowptr[N] = E;
  __syncthreads();
  for (int e = bstart + tid; e < bend; e += 256){
    int2 p = pairs[e];
    int pos = atomicAdd(&rank[p.y & 127], 1);
    col[pos] = p.x;
  }
}

// ---------------- per-layer ----------------
// k_agg: wave per node, 16 lanes x uint4 (8 bf16 feats) per gathered row,
// 4 edge-groups, 2-deep unroll. DO_BN: BN+ReLU folded into decode.
template<int DO_BN>
__device__ __forceinline__ void dec8bn(f32x2v* a, const f32x2v* scp,
    const f32x2v* bop, uint4 v){
  u32 ws[4] = {v.x, v.y, v.z, v.w};
  #pragma unroll
  for (int j = 0; j < 4; j++){
    f32x2v d = { bf2f(ws[j] & 0xffffu), bf2f(ws[j] >> 16) };
    if (DO_BN){
      d = d * scp[j] + bop[j];
      d.x = fmaxf(d.x, 0.f); d.y = fmaxf(d.y, 0.f);
    }
    a[j] += d;
  }
}

template<int DO_BN>
__global__ __launch_bounds__(256) void k_agg(const u16* __restrict__ xsrc,
    const int* __restrict__ rowptr, const int* __restrict__ col,
    u16* __restrict__ meanb, const float* __restrict__ statsh_p,
    const float* __restrict__ gamma_p, const float* __restrict__ beta_p,
    float invN, int N){
  __shared__ float scb[256];   // sc[0..127], bo[128..255]
  int tid = threadIdx.x;
  if (DO_BN){
    __shared__ float st[256];
    float sacc = 0.f;
    #pragma unroll
    for (int s2 = 0; s2 < NSH; s2++) sacc += statsh_p[s2*256 + tid];
    st[tid] = sacc;
    __syncthreads();
    if (tid < 128){
      float mu  = st[tid] * invN;
      float var = fmaf(-mu, mu, st[128 + tid] * invN);
      float s   = rsqrtf(var + EPS) * gamma_p[tid];
      scb[tid]       = s;
      scb[128 + tid] = beta_p[tid] - mu * s;
    }
    __syncthreads();
  }
  int wid  = (blockIdx.x*256 + tid) >> 6;
  if (wid >= N) return;
  int lane = tid & 63;
  int grp = lane >> 4, fl = lane & 15;   // 4 groups x 16 lanes
  f32x2v scp[4], bop[4];
  if (DO_BN){
    #pragma unroll
    for (int j = 0; j < 4; j++){
      scp[j] = (f32x2v){ scb[fl*8 + 2*j],       scb[fl*8 + 2*j + 1] };
      bop[j] = (f32x2v){ scb[128 + fl*8 + 2*j], scb[128 + fl*8 + 2*j + 1] };
    }
  }
  const u16* xf = xsrc + fl*8;          // 8 bf16 features per lane
  int r0 = rowptr[wid], r1 = rowptr[wid+1];
  f32x2v a[4];
  #pragma unroll
  for (int j = 0; j < 4; j++) a[j] = (f32x2v){0.f, 0.f};
  int e = r0 + grp;
  for (; e + 4 < r1; e += 8){
    uint4 v = *(const uint4*)(xf + (size_t)col[e]*H);
    uint4 u = *(const uint4*)(xf + (size_t)col[e+4]*H);
    dec8bn<DO_BN>(a, scp, bop, v);
    dec8bn<DO_BN>(a, scp, bop, u);
  }
  if (e < r1){
    uint4 v = *(const uint4*)(xf + (size_t)col[e]*H);
    dec8bn<DO_BN>(a, scp, bop, v);
  }
  #pragma unroll
  for (int j = 0; j < 4; j++){
    a[j].x += __shfl_xor(a[j].x, 16, 64); a[j].y += __shfl_xor(a[j].y, 16, 64);
    a[j].x += __shfl_xor(a[j].x, 32, 64); a[j].y += __shfl_xor(a[j].y, 32, 64);
  }
  if (grp == 0){
    float invc = 1.0f / (float)max(r1 - r0, 1);
    uint4 o;
    o.x = pack2(a[0].x*invc, a[0].y*invc);
    o.y = pack2(a[1].x*invc, a[1].y*invc);
    o.z = pack2(a[2].x*invc, a[2].y*invc);
    o.w = pack2(a[3].x*invc, a[3].y*invc);
    *(uint4*)(meanb + (size_t)wid*H + fl*8) = o;
  }
}

// x2b_out[n][h] (bf16, PRE-BN) = bl[h] + [meanb | bn(xsrc)] @ Wt^T.
// DO_BN: x-side A-fragments get BN+ReLU applied in-register (stats_prev).
template<int DO_BN>
__global__ __launch_bounds__(256) void k_linear(const u16* __restrict__ meanb,
    const u16* __restrict__ xsrc, const u16* __restrict__ Wt,
    const float* __restrict__ bl, u16* __restrict__ x2b,
    float* __restrict__ statsh_l, const float* __restrict__ statsh_p,
    const float* __restrict__ gamma_p, const float* __restrict__ beta_p,
    float invN, int N){
  __shared__ u16 Ws[128][WSP];         // 69.6 KB -> 2 blocks/CU
  __shared__ float Sh[128], Qh[128];
  __shared__ float st[256];
  __shared__ float scl[128], bol[128];
  int tid = threadIdx.x;
  if (tid < 128){ Sh[tid] = 0.f; Qh[tid] = 0.f; }
  int lane = tid & 63, w = tid >> 6;
  int mlane = lane & 15, quad = lane >> 4;
  int node = blockIdx.x*64 + w*16 + mlane;
  const u16* arow_m = meanb + (size_t)node*H + quad*8;
  const u16* arow_x = xsrc + (size_t)node*H + quad*8;
  bf16x8 af[8];
  #pragma unroll
  for (int kk = 0; kk < 4; kk++){
    af[kk]     = *(const bf16x8*)(arow_m + kk*32);
    af[kk + 4] = *(const bf16x8*)(arow_x + kk*32);
  }
  #pragma unroll
  for (int j = 0; j < 16; j++){
    int u = tid + j*256;
    int row = u >> 5, seg = u & 31;
    uint4 v = ((const uint4*)(Wt + (size_t)row*256))[seg];
    *(uint4*)&Ws[row][seg*8] = v;
  }
  if (DO_BN){
    float sacc = 0.f;
    #pragma unroll
    for (int s2 = 0; s2 < NSH; s2++) sacc += statsh_p[s2*256 + tid];
    st[tid] = sacc;
  }
  __syncthreads();
  if (DO_BN){
    if (tid < 128){
      float mu  = st[tid] * invN;
      float var = fmaf(-mu, mu, st[128 + tid] * invN);
      float s   = rsqrtf(var + EPS) * gamma_p[tid];
      scl[tid] = s;
      bol[tid] = beta_p[tid] - mu * s;
    }
    __syncthreads();
    #pragma unroll
    for (int kk = 0; kk < 4; kk++){
      bf16x8 raw = af[kk + 4];
      bf16x8 outv;
      #pragma unroll
      for (int j = 0; j < 8; j++){
        int h = kk*32 + quad*8 + j;
        float d = bf2f((u32)(u16)raw[j]);
        float y = fmaxf(fmaf(d, scl[h], bol[h]), 0.f);
        outv[j] = (short)f2bf(y);
      }
      af[kk + 4] = outv;
    }
  }
  f32x4 acc[8];
  #pragma unroll
  for (int t = 0; t < 8; t++) acc[t] = (f32x4){0.f, 0.f, 0.f, 0.f};
  #pragma unroll
  for (int kk = 0; kk < 8; kk++){
    #pragma unroll
    for (int t = 0; t < 8; t++){
      bf16x8 b = *(const bf16x8*)&Ws[t*16 + mlane][kk*32 + quad*8];
      acc[t] = __builtin_amdgcn_mfma_f32_16x16x32_bf16(af[kk], b, acc[t], 0, 0, 0);
    }
  }
  #pragma unroll
  for (int t = 0; t < 8; t++){
    int h = t*16 + mlane;
    float bv = bl[h];
    float s = 0.f, q = 0.f;
    #pragma unroll
    for (int r = 0; r < 4; r++){
      int nd = blockIdx.x*64 + w*16 + quad*4 + r;
      if (nd < N){
        float v = acc[t][r] + bv;
        x2b[(size_t)nd*H + h] = f2bf(v);
        s += v; q = fmaf(v, v, q);
      }
    }
    s += __shfl_xor(s, 16, 64); s += __shfl_xor(s, 32, 64);
    q += __shfl_xor(q, 16, 64); q += __shfl_xor(q, 32, 64);
    if (quad == 0){
      atomicAdd(&Sh[h], s);
      atomicAdd(&Qh[h], q);
    }
  }
  __syncthreads();
  {
    float v = (tid < 128) ? Sh[tid] : Qh[tid - 128];
    atomicAdd(&statsh_l[(blockIdx.x & (NSH-1))*256 + tid], v);
  }
}

// fused final BN+ReLU + attention scores + cluster partials.
// One block per (g,b); processes its strided nodes in 8-node chunks:
// stage post-BN rows -> LDS, score GEMV (write escore for k_out), accumulate.
__global__ __launch_bounds__(256) void k_clust(const u16* __restrict__ x2b,
    const float* __restrict__ statsh_l, const float* __restrict__ gamma,
    const float* __restrict__ beta,
    const float* __restrict__ attn_W, const float* __restrict__ attn_b,
    const int* __restrict__ gs, float* __restrict__ escore,
    float* __restrict__ partial, float invN){
  __shared__ float st[256];
  __shared__ float scb[128], bob[128];
  __shared__ float aw[H*C];
  __shared__ float ab[C];
  __shared__ float xs[8][132];
  __shared__ float es[8][16];
  int tid = threadIdx.x;
  {
    float sacc = 0.f;
    #pragma unroll
    for (int s2 = 0; s2 < NSH; s2++) sacc += statsh_l[s2*256 + tid];
    st[tid] = sacc;
  }
  #pragma unroll
  for (int j = 0; j < 8; j++) aw[tid + j*256] = attn_W[tid + j*256];
  if (tid < C) ab[tid] = attn_b[tid];
  __syncthreads();
  if (tid < 128){
    float mu  = st[tid] * invN;
    float var = fmaf(-mu, mu, st[128 + tid] * invN);
    float s   = rsqrtf(var + EPS) * gamma[tid];
    scb[tid] = s;
    bob[tid] = beta[tid] - mu * s;
  }
  __syncthreads();
  int g = blockIdx.x >> 4, b = blockIdx.x & 15;
  int h = tid & 127, cg = tid >> 7;
  int a = gs[g], e2 = gs[g+1];
  float acc[8] = {0,0,0,0,0,0,0,0};
  int ln = tid >> 5, q = tid & 31, h4 = q*4;
  for (int base = a + b; base < e2; base += 128){   // 8 nodes, stride 16
    // ---- stage: post-BN rows of nodes base + k*16 ----
    {
      int n = base + ln*16;
      if (n < e2){
        uint2 o2 = ((const uint2*)x2b)[(size_t)n*32 + q];
        float vv[4] = {bf2f(o2.x & 0xffff), bf2f(o2.x >> 16),
                       bf2f(o2.y & 0xffff), bf2f(o2.y >> 16)};
        #pragma unroll
        for (int j = 0; j < 4; j++)
          xs[ln][h4+j] = fmaxf(fmaf(vv[j], scb[h4+j], bob[h4+j]), 0.0f);
      }
    }
    __syncthreads();
    // ---- scores ----
    if (tid < 128){
      int n2 = tid >> 4, c = tid & 15;
      int n = base + n2*16;
      if (n < e2){
        float sacc = ab[c];
        #pragma unroll 4
        for (int k = 0; k < H; k++)
          sacc = fmaf(xs[n2][k], aw[k*C + c], sacc);
        float ev = __expf(sacc);
        es[n2][c] = ev;
        escore[(size_t)n*C + c] = ev;
      }
    }
    __syncthreads();
    // ---- accumulate partials ----
    #pragma unroll
    for (int k = 0; k < 8; k++){
      int n = base + k*16;
      if (n < e2){
        float xv = xs[k][h];
        const float* ep = &es[k][cg*8];
        acc[0] = fmaf(ep[0], xv, acc[0]);
        acc[1] = fmaf(ep[1], xv, acc[1]);
        acc[2] = fmaf(ep[2], xv, acc[2]);
        acc[3] = fmaf(ep[3], xv, acc[3]);
        acc[4] = fmaf(ep[4], xv, acc[4]);
        acc[5] = fmaf(ep[5], xv, acc[5]);
        acc[6] = fmaf(ep[6], xv, acc[6]);
        acc[7] = fmaf(ep[7], xv, acc[7]);
      }
    }
    __syncthreads();   // xs/es reuse next chunk
  }
  int c0 = cg*8;
  float* dst = partial + (((size_t)(g*16 + b))*C)*H + h;
  #pragma unroll
  for (int r = 0; r < 8; r++)
    dst[(size_t)(c0 + r)*H] = acc[r];
}

// k_out with fused denom (sum of escore over the graph's nodes per cluster)
__global__ __launch_bounds__(256) void k_out(const float* __restrict__ partial,
    const float* __restrict__ escore, const int* __restrict__ gs,
    const float* __restrict__ out_W, const float* __restrict__ out_b,
    float* __restrict__ out){
  __shared__ float cs[2][128];
  __shared__ float dsum[4];
  int tid = threadIdx.x;
  int r = tid >> 7, h = tid & 127;
  int row = blockIdx.x*2 + r;          // (g,c) flat
  int g = row >> 4, c = row & 15;
  int a = gs[g], b2 = gs[g+1];
  // denom
  float s = 0.f;
  for (int n = a + h; n < b2; n += 128) s += escore[(size_t)n*C + c];
  s += __shfl_xor(s, 1, 64);  s += __shfl_xor(s, 2, 64);
  s += __shfl_xor(s, 4, 64);  s += __shfl_xor(s, 8, 64);
  s += __shfl_xor(s, 16, 64); s += __shfl_xor(s, 32, 64);
  if ((tid & 63) == 0) dsum[tid >> 6] = s;
  // cluster sum reduce
  float p = 0.f;
  for (int b = 0; b < 16; b++)
    p += partial[(((size_t)(g*16 + b))*C + c)*H + h];
  cs[r][h] = p;
  __syncthreads();
  float gden = dsum[r*2] + dsum[r*2 + 1];
  float inv = gden > 0.f ? 1.0f / gden : 0.f;
  float acc = 0.f;
  for (int hh = 0; hh < H; hh++)
    acc = fmaf(cs[r][hh], out_W[hh*ODIM + h], acc);
  out[(size_t)row*ODIM + h] = fmaf(acc, inv, out_b[h]);
}

// ---------------- host ----------------
extern "C" void kernel_launch(void* const* d_in, const int* in_sizes, int n_in,
                              void* d_out, int out_size, void* d_ws, size_t ws_size,
                              hipStream_t stream){
  const float* emb    = (const float*)d_in[0];
  const float* Wl     = (const float*)d_in[1];
  const float* bl     = (const float*)d_in[2];
  const float* Wr     = (const float*)d_in[3];
  const float* gamma  = (const float*)d_in[4];
  const float* beta   = (const float*)d_in[5];
  const float* attn_W = (const float*)d_in[6];
  const float* attn_b = (const float*)d_in[7];
  const float* out_W  = (const float*)d_in[8];
  const float* out_b  = (const float*)d_in[9];
  const int* deg    = (const int*)d_in[10];
  const int* ei     = (const int*)d_in[11];
  const int* batch  = (const int*)d_in[12];
  float* out = (float*)d_out;

  const int N = in_sizes[10];
  const int E = in_sizes[11] / 2;
  const int L = in_sizes[1] / (H*H);
  const int B = out_size / (C*ODIM);
  const int NB = (N + 127) >> 7;        // buckets of 128 nodes
  const int nbh = NB * NP;              // blkhist elements
  const int chunk = (E + NP - 1) / NP;  // edges per hist/place block
  const int nblkL = (N + 63) / 64;      // k_linear grid

  size_t off = 0;
  auto alloc = [&](size_t bytes) -> void* {
    void* p = (char*)d_ws + off;
    off += (bytes + 255) & ~(size_t)255;
    return p;
  };
  u16*   xb     = (u16*)  alloc((size_t)N*H*2);       // embed (layer-0 src)
  u16*   x2bA   = (u16*)  alloc((size_t)N*H*2);       // ping
  u16*   x2bB   = (u16*)  alloc((size_t)N*H*2);       // pong
  u16*   meanb  = (u16*)  alloc((size_t)N*H*2);
  int2*  pairs  = (int2*) alloc((size_t)E*8);
  float* partial= (float*)alloc((size_t)B*16*C*H*4);
  u16*   Wt     = (u16*)  alloc((size_t)L*H*256*2);
  float* escore = (float*)alloc((size_t)N*C*4);
  int*   col    = (int*)  alloc((size_t)E*4);
  int*   rowptr = (int*)  alloc((size_t)(N+1)*4);
  int*   blkhist= (int*)  alloc((size_t)nbh*4);
  int*   bases  = (int*)  alloc((size_t)nbh*4);
  int*   bsum   = (int*)  alloc(256*4);
  int*   gs     = (int*)  alloc((size_t)(B+1)*4);
  float* statsh = (float*)alloc((size_t)L*NSH*256*4);

  // fused setup
  int gz = L*NSH;
  int g0 = gz + (N*32 + 255)/256;
  int g1 = g0 + (N + 255)/256;
  int g2 = g1 + L*16;
  int gT = g2 + NP;
  hipLaunchKernelGGL(k_setup, dim3(gT), dim3(256), 0, stream,
                     emb, deg, xb, batch, gs, Wl, Wr, Wt, ei, blkhist,
                     statsh, N, B, NB, E, chunk, gz, g0, g1, g2);
  int nblkS = (nbh + 1023) / 1024;
  hipLaunchKernelGGL(k_scanA, dim3(nblkS), dim3(256), 0, stream, blkhist, bases, bsum, nbh);
  hipLaunchKernelGGL(k_place, dim3(NP), dim3(256), 0, stream,
                     ei, bases, bsum, pairs, NB, E, chunk, nblkS);
  hipLaunchKernelGGL(k_cnt_place, dim3(NB), dim3(256), 0, stream,
                     pairs, bases, bsum, rowptr, col, NB, N, E, nblkS);

  float invN = 1.0f / (float)N;
  u16* x2buf[2] = {x2bA, x2bB};
  int nblkA = (N + 3) / 4;
  for (int l = 0; l < L; l++){
    const u16* src = (l == 0) ? xb : x2buf[(l-1) & 1];
    u16* dst = x2buf[l & 1];
    float* sh_l = statsh + (size_t)l*NSH*256;
    const float* sh_p = (l == 0) ? nullptr : statsh + (size_t)(l-1)*NSH*256;
    const float* gp = gamma + (size_t)(l-1)*H;
    const float* bp = beta  + (size_t)(l-1)*H;
    if (l == 0){
      k_agg<0><<<dim3(nblkA), dim3(256), 0, stream>>>(
          src, rowptr, col, meanb, nullptr, nullptr, nullptr, invN, N);
      k_linear<0><<<dim3(nblkL), dim3(256), 0, stream>>>(
          meanb, src, Wt + (size_t)l*H*256, bl + (size_t)l*H, dst,
          sh_l, nullptr, nullptr, nullptr, invN, N);
    } else {
      k_agg<1><<<dim3(nblkA), dim3(256), 0, stream>>>(
          src, rowptr, col, meanb, sh_p, gp, bp, invN, N);
      k_linear<1><<<dim3(nblkL), dim3(256), 0, stream>>>(
          meanb, src, Wt + (size_t)l*H*256, bl + (size_t)l*H, dst,
          sh_l, sh_p, gp, bp, invN, N);
    }
  }
  hipLaunchKernelGGL(k_clust, dim3(B*16), dim3(256), 0, stream,
                     x2buf[(L-1) & 1], statsh + (size_t)(L-1)*NSH*256,
                     gamma + (size_t)(L-1)*H, beta + (size_t)(L-1)*H,
                     attn_W, attn_b, gs, escore, partial, invN);
  hipLaunchKernelGGL(k_out,   dim3(B*C/2), dim3(256), 0, stream,
                     partial, escore, gs, out_W, out_b, out);
}